// Round 11
// baseline (457.052 us; speedup 1.0000x reference)
//
#include <hip/hip_runtime.h>

#define NN 20000
#define NP 20096   // padded rows (multiple of 128)
#define NE 320000
#define DD 512

typedef __bf16 bf16x8 __attribute__((ext_vector_type(8)));
typedef float f32x4 __attribute__((ext_vector_type(4)));
typedef unsigned short u16;

__device__ __forceinline__ float sigmoidf_(float x) { return 1.f / (1.f + expf(-x)); }

__device__ __forceinline__ unsigned bf16pair(float a, float b) {
  unsigned ua = __builtin_bit_cast(unsigned, a);
  unsigned ub = __builtin_bit_cast(unsigned, b);
  ua = (ua + 0x7FFFu + ((ua >> 16) & 1u)) >> 16;
  ub = (ub + 0x7FFFu + ((ub >> 16) & 1u)) >> 16;
  return ua | (ub << 16);
}
__device__ __forceinline__ u16 bf16one(float a) {
  unsigned ua = __builtin_bit_cast(unsigned, a);
  return (u16)((ua + 0x7FFFu + ((ua >> 16) & 1u)) >> 16);
}
__device__ __forceinline__ float bflo(unsigned w) { return __builtin_bit_cast(float, w << 16); }
__device__ __forceinline__ float bfhi(unsigned w) { return __builtin_bit_cast(float, w & 0xFFFF0000u); }
__device__ __forceinline__ float bf2f(u16 v) { return __builtin_bit_cast(float, (unsigned)v << 16); }

__device__ __forceinline__ void gload16(const void* g, void* l) {
  __builtin_amdgcn_global_load_lds(
      (const __attribute__((address_space(1))) unsigned int*)g,
      (__attribute__((address_space(3))) unsigned int*)l, 16, 0, 0);
}

// ---------------- fused setup: cvt(X,H)->bf16 | init deg/cnt | 6 weight transposes ----
#define CVT_B 10000   // 2*NN*DD/8/256
#define INIT_B 79     // ceil(NN/256)
#define WT_B 1536     // 6 * 16 * 16
__global__ __launch_bounds__(256) void k_setup(
    const float* __restrict__ X, const float* __restrict__ H,
    u16* __restrict__ Xb, u16* __restrict__ Hb,
    const float* __restrict__ W0, const float* __restrict__ W1,
    const float* __restrict__ W2, const float* __restrict__ W3,
    const float* __restrict__ W4, const float* __restrict__ W5,
    u16* __restrict__ T, float* __restrict__ deg, int* __restrict__ cnt) {
  __shared__ float t[32][33];
  int b = blockIdx.x;
  if (b < CVT_B) {
    const int n8 = NN * DD / 8;
    int i = b * 256 + threadIdx.x;
    const float* src = (i < n8) ? X : H;
    u16* dst = (i < n8) ? Xb : Hb;
    int k = (i < n8) ? i : i - n8;
    const float4* s = (const float4*)src;
    float4 v0 = s[k * 2], v1 = s[k * 2 + 1];
    uint4 o = {bf16pair(v0.x, v0.y), bf16pair(v0.z, v0.w),
               bf16pair(v1.x, v1.y), bf16pair(v1.z, v1.w)};
    ((uint4*)dst)[k] = o;
  } else if (b < CVT_B + INIT_B) {
    int i = (b - CVT_B) * 256 + threadIdx.x;
    if (i < NN) { deg[i] = 1.0f; cnt[i] = 0; }
  } else {
    int wb = b - CVT_B - INIT_B;          // [0, 1536)
    const float* Wsrc;
    switch (wb >> 8) {
      case 0: Wsrc = W0; break; case 1: Wsrc = W1; break; case 2: Wsrc = W2; break;
      case 3: Wsrc = W3; break; case 4: Wsrc = W4; break; default: Wsrc = W5; break;
    }
    u16* Wt = T + (size_t)(wb >> 8) * 262144;
    int rb = wb & 255;
    int kb = (rb & 15) * 32, nb = (rb >> 4) * 32;
    int tx = threadIdx.x & 31, ty = threadIdx.x >> 5;
#pragma unroll
    for (int i2 = 0; i2 < 4; ++i2)
      t[ty * 4 + i2][tx] = Wsrc[(size_t)(kb + ty * 4 + i2) * 512 + nb + tx];
    __syncthreads();
#pragma unroll
    for (int i2 = 0; i2 < 4; ++i2)
      Wt[(size_t)(nb + ty * 4 + i2) * 512 + kb + tx] = bf16one(t[tx][ty * 4 + i2]);
  }
}

// ---------------- degree / CSR ----------------
__global__ void k_accum(const int* col, const float* w, float* deg, int* cnt) {
  int e = blockIdx.x * 256 + threadIdx.x;
  if (e < NE) {
    int c = col[e];
    atomicAdd(&deg[c], w[e]);
    atomicAdd(&cnt[c], 1);
  }
}

__global__ void k_scan(const int* cnt, int* ptr, int* pos) {
  __shared__ int sdata[1024];
  const int ITEMS = (NN + 1023) / 1024;
  int tid = threadIdx.x;
  int base = tid * ITEMS;
  int s = 0;
  for (int j = 0; j < ITEMS; ++j) { int i = base + j; if (i < NN) s += cnt[i]; }
  sdata[tid] = s;
  __syncthreads();
  for (int off = 1; off < 1024; off <<= 1) {
    int v = 0;
    if (tid >= off) v = sdata[tid - off];
    __syncthreads();
    sdata[tid] += v;
    __syncthreads();
  }
  int run = (tid == 0) ? 0 : sdata[tid - 1];
  for (int j = 0; j < ITEMS; ++j) {
    int i = base + j;
    if (i < NN) { ptr[i] = run; pos[i] = run; run += cnt[i]; }
  }
  if (tid == 0) ptr[NN] = NE;
}

__global__ void k_scatter(const int* row, const int* col, const float* w, const float* deg,
                          int* pos, int* erow, float* enorm) {
  int e = blockIdx.x * 256 + threadIdx.x;
  if (e < NE) {
    int r = row[e], c = col[e];
    int slot = atomicAdd(&pos[c], 1);
    erow[slot] = r;
    enorm[slot] = rsqrtf(deg[r]) * w[e] * rsqrtf(deg[c]);
  }
}

// ---------------- XCD-sliced aggregation, 16B/lane, unroll-2 stride-8 loop ----------
__global__ __launch_bounds__(256) void k_agg_dual_s2(const u16* __restrict__ Xb,
                                                     const u16* __restrict__ Hb,
                                                     const int* __restrict__ ptr,
                                                     const int* __restrict__ erow,
                                                     const float* __restrict__ enorm,
                                                     const float* __restrict__ deg,
                                                     u16* __restrict__ AXb,
                                                     u16* __restrict__ AHb) {
  int bid = blockIdx.x;
  int slice = bid & 7, nb = bid >> 3;
  int w = threadIdx.x >> 6, lane = threadIdx.x & 63;
  int node = nb * 4 + w;
  int g = lane >> 3, cl = lane & 7;
  int soff = slice * 8 + cl;                 // uint4 index within a 64-uint4 row
  const uint4* X4 = (const uint4*)Xb;
  const uint4* H4 = (const uint4*)Hb;
  float s = rsqrtf(deg[node]), s2 = s * s;
  int pe = ptr[node];
  int items = ptr[node + 1] - pe + 1;        // self + deg

  float ax[8] = {}, ah[8] = {};
  auto accum = [&](float nm, uint4 xv, uint4 hv) {
    unsigned xw[4] = {xv.x, xv.y, xv.z, xv.w};
    unsigned hw[4] = {hv.x, hv.y, hv.z, hv.w};
#pragma unroll
    for (int j = 0; j < 4; ++j) {
      ax[2 * j]     += nm * bflo(xw[j]);
      ax[2 * j + 1] += nm * bfhi(xw[j]);
      ah[2 * j]     += nm * bflo(hw[j]);
      ah[2 * j + 1] += nm * bfhi(hw[j]);
    }
  };

  int it = g;
  for (; it + 8 < items; it += 16) {
    int rA = node; float nA = s2;
    if (it > 0) { rA = erow[pe + it - 1]; nA = enorm[pe + it - 1]; }
    int eB = pe + it + 7;
    int rB = erow[eB]; float nB = enorm[eB];
    uint4 xA = X4[(size_t)rA * 64 + soff];
    uint4 hA = H4[(size_t)rA * 64 + soff];
    uint4 xB = X4[(size_t)rB * 64 + soff];
    uint4 hB = H4[(size_t)rB * 64 + soff];
    accum(nA, xA, hA);
    accum(nB, xB, hB);
  }
  if (it < items) {
    int rA = node; float nA = s2;
    if (it > 0) { rA = erow[pe + it - 1]; nA = enorm[pe + it - 1]; }
    accum(nA, X4[(size_t)rA * 64 + soff], H4[(size_t)rA * 64 + soff]);
  }

#pragma unroll
  for (int st = 8; st < 64; st <<= 1) {
#pragma unroll
    for (int j = 0; j < 8; ++j) {
      ax[j] += __shfl_xor(ax[j], st, 64);
      ah[j] += __shfl_xor(ah[j], st, 64);
    }
  }

  if (g == 0) {
    uint4 ox;
    ox.x = bf16pair(ax[0], ax[1]); ox.y = bf16pair(ax[2], ax[3]);
    ox.z = bf16pair(ax[4], ax[5]); ox.w = bf16pair(ax[6], ax[7]);
    ((uint4*)AXb)[(size_t)node * 64 + soff] = ox;
  } else if (g == 1) {
    uint4 oh;
    oh.x = bf16pair(ah[0], ah[1]); oh.y = bf16pair(ah[2], ah[3]);
    oh.z = bf16pair(ah[4], ah[5]); oh.w = bf16pair(ah[6], ah[7]);
    ((uint4*)AHb)[(size_t)node * 64 + soff] = oh;
  }
}

__global__ __launch_bounds__(256) void k_agg_single_s2(const u16* __restrict__ Sb,
                                                       const int* __restrict__ ptr,
                                                       const int* __restrict__ erow,
                                                       const float* __restrict__ enorm,
                                                       const float* __restrict__ deg,
                                                       u16* __restrict__ Ab) {
  int bid = blockIdx.x;
  int slice = bid & 7, nb = bid >> 3;
  int w = threadIdx.x >> 6, lane = threadIdx.x & 63;
  int node = nb * 4 + w;
  int g = lane >> 3, cl = lane & 7;
  int soff = slice * 8 + cl;
  const uint4* S4 = (const uint4*)Sb;
  float s = rsqrtf(deg[node]), s2 = s * s;
  int pe = ptr[node];
  int items = ptr[node + 1] - pe + 1;

  float ax[8] = {};
  auto accum = [&](float nm, uint4 xv) {
    unsigned xw[4] = {xv.x, xv.y, xv.z, xv.w};
#pragma unroll
    for (int j = 0; j < 4; ++j) {
      ax[2 * j]     += nm * bflo(xw[j]);
      ax[2 * j + 1] += nm * bfhi(xw[j]);
    }
  };

  int it = g;
  for (; it + 8 < items; it += 16) {
    int rA = node; float nA = s2;
    if (it > 0) { rA = erow[pe + it - 1]; nA = enorm[pe + it - 1]; }
    int eB = pe + it + 7;
    int rB = erow[eB]; float nB = enorm[eB];
    uint4 xA = S4[(size_t)rA * 64 + soff];
    uint4 xB = S4[(size_t)rB * 64 + soff];
    accum(nA, xA);
    accum(nB, xB);
  }
  if (it < items) {
    int rA = node; float nA = s2;
    if (it > 0) { rA = erow[pe + it - 1]; nA = enorm[pe + it - 1]; }
    accum(nA, S4[(size_t)rA * 64 + soff]);
  }

#pragma unroll
  for (int st = 8; st < 64; st <<= 1) {
#pragma unroll
    for (int j = 0; j < 8; ++j) ax[j] += __shfl_xor(ax[j], st, 64);
  }

  if (g == 0) {
    uint4 ox;
    ox.x = bf16pair(ax[0], ax[1]); ox.y = bf16pair(ax[2], ax[3]);
    ox.z = bf16pair(ax[4], ax[5]); ox.w = bf16pair(ax[6], ax[7]);
    ((uint4*)Ab)[(size_t)node * 64 + soff] = ox;
  }
}

// ---------------- fused big GEMM: 12 col-blocks (z | r | Mx), 2-phase dbuf ----------
// seg 0 (c 0-3):  Zb  = bf16(sigmoid(AX@Wxz + AH@Whz + bxz+bhz))
// seg 1 (c 4-7):  HRb = bf16(Hb * sigmoid(AX@Wxr + AH@Whr + bxr+bhr))  [Hb bf16]
// seg 2 (c 8-11): Mxb = bf16(AX@Wxh)          (bias added in final GEMM)
// T3 minimum 2-phase: STAGE(next half) issued before COMPUTE(cur); one barrier/step.
__global__ __launch_bounds__(256) void k_gemm_big(
    const u16* __restrict__ AXb, const u16* __restrict__ AHb,
    const u16* __restrict__ WtAll,
    const float* __restrict__ bxz, const float* __restrict__ bhz,
    const float* __restrict__ bxr, const float* __restrict__ bhr,
    const u16* __restrict__ Hb,
    u16* __restrict__ Zb, u16* __restrict__ HRb, u16* __restrict__ Mxb) {
  extern __shared__ unsigned char smem[];  // 2 x (A 16KB | B 16KB) = 64KB
  const int tid = threadIdx.x;
  const int lane = tid & 63, w = tid >> 6;
  const int wr = w >> 1, wc = w & 1;

  // bijective XCD-chunked map over 1884 = 157 row-blocks x 12 col-blocks
  const int q = 235, r8 = 4;  // 1884 = 8*235+4
  const int xcd = blockIdx.x & 7, ii = blockIdx.x >> 3;
  const int start = (xcd < r8) ? xcd * (q + 1) : r8 * (q + 1) + (xcd - r8) * q;
  const int wk = start + ii;
  const int rowBase = (wk / 12) * 128;
  const int c = wk % 12;
  const int seg = c >> 2;
  const int colBase = (c & 3) * 128;

  const u16* W1;
  const u16* W2;
  if (seg == 0)      { W1 = WtAll;                     W2 = WtAll + 262144; }
  else if (seg == 1) { W1 = WtAll + 2 * 262144;        W2 = WtAll + 3 * 262144; }
  else               { W1 = WtAll + 4 * 262144;        W2 = nullptr; }
  const int NK = (seg == 2) ? 8 : 16;

  f32x4 acc[4][4] = {};

  const int lrow = lane & 15;
  const int lkb = (lane >> 4) << 4;
  const int swz = (lane & 7) << 4;
  const int srow = w * 32 + (lane >> 3);
  const int scol = (((lane & 7) ^ (lane >> 3)) << 4);

  auto STAGE = [&](int kt, int buf) {
    int pass = kt >> 3;
    size_t ko = (size_t)(kt & 7) << 7;  // (kt&7)*64 cols * 2B
    const u16* A = pass ? AHb : AXb;
    const u16* Wt = pass ? W2 : W1;
    const char* Ab = (const char*)A + (size_t)(rowBase + srow) * 1024 + scol + ko;
    const char* Bb = (const char*)Wt + (size_t)(colBase + srow) * 1024 + scol + ko;
    int bo = buf << 15;
#pragma unroll
    for (int t = 0; t < 4; ++t) {
      gload16(Ab + (size_t)t * 8192, &smem[bo + w * 4096 + t * 1024]);
      gload16(Bb + (size_t)t * 8192, &smem[bo + 16384 + w * 4096 + t * 1024]);
    }
  };
  auto COMPUTE = [&](int buf) {
    int bo = buf << 15;
#pragma unroll
    for (int ks = 0; ks < 2; ++ks) {
      bf16x8 af[4], bfr[4];
#pragma unroll
      for (int fm = 0; fm < 4; ++fm) {
        int row = wr * 64 + fm * 16 + lrow;
        af[fm] = *(const bf16x8*)&smem[bo + row * 128 + (((ks << 6) + lkb) ^ swz)];
      }
#pragma unroll
      for (int fn = 0; fn < 4; ++fn) {
        int row = wc * 64 + fn * 16 + lrow;
        bfr[fn] = *(const bf16x8*)&smem[bo + 16384 + row * 128 + (((ks << 6) + lkb) ^ swz)];
      }
#pragma unroll
      for (int fm = 0; fm < 4; ++fm)
#pragma unroll
        for (int fn = 0; fn < 4; ++fn)
          acc[fm][fn] = __builtin_amdgcn_mfma_f32_16x16x32_bf16(af[fm], bfr[fn], acc[fm][fn], 0, 0, 0);
    }
  };

  STAGE(0, 0);
  __syncthreads();
  for (int kt = 0; kt < NK; ++kt) {
    if (kt + 1 < NK) STAGE(kt + 1, (kt + 1) & 1);
    COMPUTE(kt & 1);
    __syncthreads();
  }

  // epilogue: col=lane&15, row=(lane>>4)*4+reg
#pragma unroll
  for (int fm = 0; fm < 4; ++fm) {
    int rbase = rowBase + wr * 64 + fm * 16 + ((lane >> 4) << 2);
#pragma unroll
    for (int fn = 0; fn < 4; ++fn) {
      int col = colBase + wc * 64 + fn * 16 + lrow;
      float bb = (seg == 0) ? (bxz[col] + bhz[col])
               : (seg == 1) ? (bxr[col] + bhr[col]) : 0.f;
#pragma unroll
      for (int r = 0; r < 4; ++r) {
        int row = rbase + r;
        if (row >= NN) continue;
        size_t idx = (size_t)row * 512 + col;
        float a = acc[fm][fn][r] + bb;
        if (seg == 0) {
          Zb[idx] = bf16one(sigmoidf_(a));
        } else if (seg == 1) {
          HRb[idx] = bf16one(bf2f(Hb[idx]) * sigmoidf_(a));
        } else {
          Mxb[idx] = bf16one(a);
        }
      }
    }
  }
}

// ---------------- final GEMM: K=512, 2-phase dbuf, out = z*H + (1-z)*tanh(...) ----
__global__ __launch_bounds__(256) void k_gemm_fin(
    const u16* __restrict__ AHRb, const u16* __restrict__ Whh_t,
    const float* __restrict__ bxh, const float* __restrict__ bhh,
    const float* __restrict__ H, const u16* __restrict__ Zb,
    const u16* __restrict__ Mxb, float* __restrict__ out) {
  extern __shared__ unsigned char smem[];  // 64KB dbuf
  const int tid = threadIdx.x;
  const int lane = tid & 63, w = tid >> 6;
  const int wr = w >> 1, wc = w & 1;

  const int q = 78, r8 = 4;  // 628 = 8*78+4
  const int xcd = blockIdx.x & 7, ii = blockIdx.x >> 3;
  const int start = (xcd < r8) ? xcd * (q + 1) : r8 * (q + 1) + (xcd - r8) * q;
  const int wk = start + ii;
  const int rowBase = (wk >> 2) * 128;
  const int colBase = (wk & 3) * 128;

  f32x4 acc[4][4] = {};

  const int lrow = lane & 15;
  const int lkb = (lane >> 4) << 4;
  const int swz = (lane & 7) << 4;
  const int srow = w * 32 + (lane >> 3);
  const int scol = (((lane & 7) ^ (lane >> 3)) << 4);

  const char* Abase = (const char*)AHRb + (size_t)(rowBase + srow) * 1024 + scol;
  const char* Bbase = (const char*)Whh_t + (size_t)(colBase + srow) * 1024 + scol;

  auto STAGE = [&](int kt, int buf) {
    size_t ko = (size_t)kt << 7;
    int bo = buf << 15;
#pragma unroll
    for (int t = 0; t < 4; ++t) {
      gload16(Abase + (size_t)t * 8192 + ko, &smem[bo + w * 4096 + t * 1024]);
      gload16(Bbase + (size_t)t * 8192 + ko, &smem[bo + 16384 + w * 4096 + t * 1024]);
    }
  };
  auto COMPUTE = [&](int buf) {
    int bo = buf << 15;
#pragma unroll
    for (int ks = 0; ks < 2; ++ks) {
      bf16x8 af[4], bfr[4];
#pragma unroll
      for (int fm = 0; fm < 4; ++fm) {
        int row = wr * 64 + fm * 16 + lrow;
        af[fm] = *(const bf16x8*)&smem[bo + row * 128 + (((ks << 6) + lkb) ^ swz)];
      }
#pragma unroll
      for (int fn = 0; fn < 4; ++fn) {
        int row = wc * 64 + fn * 16 + lrow;
        bfr[fn] = *(const bf16x8*)&smem[bo + 16384 + row * 128 + (((ks << 6) + lkb) ^ swz)];
      }
#pragma unroll
      for (int fm = 0; fm < 4; ++fm)
#pragma unroll
        for (int fn = 0; fn < 4; ++fn)
          acc[fm][fn] = __builtin_amdgcn_mfma_f32_16x16x32_bf16(af[fm], bfr[fn], acc[fm][fn], 0, 0, 0);
    }
  };

  STAGE(0, 0);
  __syncthreads();
  for (int kt = 0; kt < 8; ++kt) {
    if (kt + 1 < 8) STAGE(kt + 1, (kt + 1) & 1);
    COMPUTE(kt & 1);
    __syncthreads();
  }

#pragma unroll
  for (int fm = 0; fm < 4; ++fm) {
    int rbase = rowBase + wr * 64 + fm * 16 + ((lane >> 4) << 2);
#pragma unroll
    for (int fn = 0; fn < 4; ++fn) {
      int col = colBase + wc * 64 + fn * 16 + lrow;
      float bb = bxh[col] + bhh[col];
#pragma unroll
      for (int r = 0; r < 4; ++r) {
        int row = rbase + r;
        if (row >= NN) continue;
        size_t idx = (size_t)row * 512 + col;
        float a = acc[fm][fn][r] + bb + bf2f(Mxb[idx]);
        float t = tanhf(a);
        float z = bf2f(Zb[idx]);
        out[idx] = z * H[idx] + (1.f - z) * t;
      }
    }
  }
}

extern "C" void kernel_launch(void* const* d_in, const int* in_sizes, int n_in,
                              void* d_out, int out_size, void* d_ws, size_t ws_size,
                              hipStream_t stream) {
  const float* X   = (const float*)d_in[0];
  const int*   ei  = (const int*)d_in[1];
  const float* ew  = (const float*)d_in[2];
  const float* H   = (const float*)d_in[3];
  const float* Wxz = (const float*)d_in[4];  const float* bxz = (const float*)d_in[5];
  const float* Whz = (const float*)d_in[6];  const float* bhz = (const float*)d_in[7];
  const float* Wxr = (const float*)d_in[8];  const float* bxr = (const float*)d_in[9];
  const float* Whr = (const float*)d_in[10]; const float* bhr = (const float*)d_in[11];
  const float* Wxh = (const float*)d_in[12]; const float* bxh = (const float*)d_in[13];
  const float* Whh = (const float*)d_in[14]; const float* bhh = (const float*)d_in[15];
  const int* row = ei;
  const int* col = ei + NE;
  float* out = (float*)d_out;

  char* base = (char*)d_ws;
  size_t o = 0;
  auto alloc = [&](size_t b) { char* p = base + o; o += (b + 255) & ~(size_t)255; return p; };
  u16* Xb   = (u16*)alloc((size_t)NP * DD * 2);  // aliases Mxb (Xb dead after agg_dual)
  u16* Hb   = (u16*)alloc((size_t)NP * DD * 2);  // aliases AHRb (Hb dead after gemm_big)
  u16* AXb  = (u16*)alloc((size_t)NP * DD * 2);
  u16* AHb  = (u16*)alloc((size_t)NP * DD * 2);
  u16* HRb  = (u16*)alloc((size_t)NP * DD * 2);
  u16* Zb   = (u16*)alloc((size_t)NP * DD * 2);
  u16* WtAll= (u16*)alloc((size_t)6 * 512 * 512 * 2);
  float* deg  = (float*)alloc(NN * 4);
  int*   cnt  = (int*)alloc(NN * 4);
  int*   ptr  = (int*)alloc((NN + 1) * 4);
  int*   pos  = (int*)alloc(NN * 4);
  int*   erow = (int*)alloc(NE * 4);
  float* enorm= (float*)alloc(NE * 4);
  u16* Mxb  = Xb;   // Xb dead after k_agg_dual_s2
  u16* AHRb = Hb;   // Hb dead after k_gemm_big (seg1 epilogue is its last reader)

  dim3 b256(256);
  int gE = (NE + 255) / 256;

  // fused setup: cvt X/H -> bf16 | init deg/cnt | 6 weight transposes
  k_setup<<<CVT_B + INIT_B + WT_B, b256, 0, stream>>>(
      X, H, Xb, Hb, Wxz, Whz, Wxr, Whr, Wxh, Whh, WtAll, deg, cnt);

  // CSR build
  k_accum<<<gE, b256, 0, stream>>>(col, ew, deg, cnt);
  k_scan<<<1, 1024, 0, stream>>>(cnt, ptr, pos);
  k_scatter<<<gE, b256, 0, stream>>>(row, col, ew, deg, pos, erow, enorm);

  // AX = Agg(X), AH = Agg(H): XCD-sliced, unroll-2 stride-8 edge loop, 16B/lane
  k_agg_dual_s2<<<40000, b256, 0, stream>>>(Xb, Hb, ptr, erow, enorm, deg, AXb, AHb);

  // fused GEMM (2-phase dbuf): Zb | HRb | Mxb
  k_gemm_big<<<1884, b256, 65536, stream>>>(AXb, AHb, WtAll, bxz, bhz, bxr, bhr,
                                            Hb, Zb, HRb, Mxb);

  // AHR = Agg(HR)
  k_agg_single_s2<<<40000, b256, 0, stream>>>(HRb, ptr, erow, enorm, deg, AHRb);

  // out = Z*H + (1-Z)*tanh(Mx + AHR@Whh + bxh + bhh)
  k_gemm_fin<<<628, b256, 65536, stream>>>(AHRb, WtAll + 5 * 262144, bxh, bhh,
                                           H, Zb, Mxb, out);
}

// Round 12
// 385.069 us; speedup vs baseline: 1.1869x; 1.1869x over previous
//
#include <hip/hip_runtime.h>

#define NN 20000
#define NP 20096   // padded rows (multiple of 128)
#define NE 320000
#define DD 512

typedef __bf16 bf16x8 __attribute__((ext_vector_type(8)));
typedef float f32x4 __attribute__((ext_vector_type(4)));
typedef float f32x2 __attribute__((ext_vector_type(2)));
typedef unsigned short u16;

__device__ __forceinline__ float sigmoidf_(float x) { return 1.f / (1.f + expf(-x)); }

__device__ __forceinline__ unsigned bf16pair(float a, float b) {
  unsigned ua = __builtin_bit_cast(unsigned, a);
  unsigned ub = __builtin_bit_cast(unsigned, b);
  ua = (ua + 0x7FFFu + ((ua >> 16) & 1u)) >> 16;
  ub = (ub + 0x7FFFu + ((ub >> 16) & 1u)) >> 16;
  return ua | (ub << 16);
}
__device__ __forceinline__ u16 bf16one(float a) {
  unsigned ua = __builtin_bit_cast(unsigned, a);
  return (u16)((ua + 0x7FFFu + ((ua >> 16) & 1u)) >> 16);
}
__device__ __forceinline__ float bflo(unsigned w) { return __builtin_bit_cast(float, w << 16); }
__device__ __forceinline__ float bfhi(unsigned w) { return __builtin_bit_cast(float, w & 0xFFFF0000u); }
__device__ __forceinline__ float bf2f(u16 v) { return __builtin_bit_cast(float, (unsigned)v << 16); }

__device__ __forceinline__ void gload16(const void* g, void* l) {
  __builtin_amdgcn_global_load_lds(
      (const __attribute__((address_space(1))) unsigned int*)g,
      (__attribute__((address_space(3))) unsigned int*)l, 16, 0, 0);
}

// ---------------- fused setup: cvt(X,H)->bf16 | init deg/cnt | 6 weight transposes ----
#define CVT_B 10000   // 2*NN*DD/8/256
#define INIT_B 79     // ceil(NN/256)
#define WT_B 1536     // 6 * 16 * 16
__global__ __launch_bounds__(256) void k_setup(
    const float* __restrict__ X, const float* __restrict__ H,
    u16* __restrict__ Xb, u16* __restrict__ Hb,
    const float* __restrict__ W0, const float* __restrict__ W1,
    const float* __restrict__ W2, const float* __restrict__ W3,
    const float* __restrict__ W4, const float* __restrict__ W5,
    u16* __restrict__ T, float* __restrict__ deg, int* __restrict__ cnt) {
  __shared__ float t[32][33];
  int b = blockIdx.x;
  if (b < CVT_B) {
    const int n8 = NN * DD / 8;
    int i = b * 256 + threadIdx.x;
    const float* src = (i < n8) ? X : H;
    u16* dst = (i < n8) ? Xb : Hb;
    int k = (i < n8) ? i : i - n8;
    const float4* s = (const float4*)src;
    float4 v0 = s[k * 2], v1 = s[k * 2 + 1];
    uint4 o = {bf16pair(v0.x, v0.y), bf16pair(v0.z, v0.w),
               bf16pair(v1.x, v1.y), bf16pair(v1.z, v1.w)};
    ((uint4*)dst)[k] = o;
  } else if (b < CVT_B + INIT_B) {
    int i = (b - CVT_B) * 256 + threadIdx.x;
    if (i < NN) { deg[i] = 1.0f; cnt[i] = 0; }
  } else {
    int wb = b - CVT_B - INIT_B;          // [0, 1536)
    const float* Wsrc;
    switch (wb >> 8) {
      case 0: Wsrc = W0; break; case 1: Wsrc = W1; break; case 2: Wsrc = W2; break;
      case 3: Wsrc = W3; break; case 4: Wsrc = W4; break; default: Wsrc = W5; break;
    }
    u16* Wt = T + (size_t)(wb >> 8) * 262144;
    int rb = wb & 255;
    int kb = (rb & 15) * 32, nb = (rb >> 4) * 32;
    int tx = threadIdx.x & 31, ty = threadIdx.x >> 5;
#pragma unroll
    for (int i2 = 0; i2 < 4; ++i2)
      t[ty * 4 + i2][tx] = Wsrc[(size_t)(kb + ty * 4 + i2) * 512 + nb + tx];
    __syncthreads();
#pragma unroll
    for (int i2 = 0; i2 < 4; ++i2)
      Wt[(size_t)(nb + ty * 4 + i2) * 512 + kb + tx] = bf16one(t[tx][ty * 4 + i2]);
  }
}

// ---------------- degree / CSR ----------------
__global__ void k_accum(const int* col, const float* w, float* deg, int* cnt) {
  int e = blockIdx.x * 256 + threadIdx.x;
  if (e < NE) {
    int c = col[e];
    atomicAdd(&deg[c], w[e]);
    atomicAdd(&cnt[c], 1);
  }
}

__global__ void k_scan(const int* cnt, int* ptr, int* pos) {
  __shared__ int sdata[1024];
  const int ITEMS = (NN + 1023) / 1024;
  int tid = threadIdx.x;
  int base = tid * ITEMS;
  int s = 0;
  for (int j = 0; j < ITEMS; ++j) { int i = base + j; if (i < NN) s += cnt[i]; }
  sdata[tid] = s;
  __syncthreads();
  for (int off = 1; off < 1024; off <<= 1) {
    int v = 0;
    if (tid >= off) v = sdata[tid - off];
    __syncthreads();
    sdata[tid] += v;
    __syncthreads();
  }
  int run = (tid == 0) ? 0 : sdata[tid - 1];
  for (int j = 0; j < ITEMS; ++j) {
    int i = base + j;
    if (i < NN) { ptr[i] = run; pos[i] = run; run += cnt[i]; }
  }
  if (tid == 0) ptr[NN] = NE;
}

__global__ void k_scatter(const int* row, const int* col, const float* w, const float* deg,
                          int* pos, int* erow, float* enorm) {
  int e = blockIdx.x * 256 + threadIdx.x;
  if (e < NE) {
    int r = row[e], c = col[e];
    int slot = atomicAdd(&pos[c], 1);
    erow[slot] = r;
    enorm[slot] = rsqrtf(deg[r]) * w[e] * rsqrtf(deg[c]);
  }
}

// ---------------- XCD-sliced aggregation, 16B/lane, unroll-2, f32x2 pk-fma accum ----
__global__ __launch_bounds__(256) void k_agg_dual_s2(const u16* __restrict__ Xb,
                                                     const u16* __restrict__ Hb,
                                                     const int* __restrict__ ptr,
                                                     const int* __restrict__ erow,
                                                     const float* __restrict__ enorm,
                                                     const float* __restrict__ deg,
                                                     u16* __restrict__ AXb,
                                                     u16* __restrict__ AHb) {
  int bid = blockIdx.x;
  int slice = bid & 7, nb = bid >> 3;
  int w = threadIdx.x >> 6, lane = threadIdx.x & 63;
  int node = nb * 4 + w;
  int g = lane >> 3, cl = lane & 7;
  int soff = slice * 8 + cl;                 // uint4 index within a 64-uint4 row
  const uint4* X4 = (const uint4*)Xb;
  const uint4* H4 = (const uint4*)Hb;
  float s = rsqrtf(deg[node]), s2 = s * s;
  int pe = ptr[node];
  int items = ptr[node + 1] - pe + 1;        // self + deg

  f32x2 ax[4] = {}, ah[4] = {};
  auto accum = [&](float nm, uint4 xv, uint4 hv) {
    unsigned xw[4] = {xv.x, xv.y, xv.z, xv.w};
    unsigned hw[4] = {hv.x, hv.y, hv.z, hv.w};
    f32x2 nm2 = {nm, nm};
#pragma unroll
    for (int j = 0; j < 4; ++j) {
      f32x2 xf = {bflo(xw[j]), bfhi(xw[j])};
      f32x2 hf = {bflo(hw[j]), bfhi(hw[j])};
      ax[j] += nm2 * xf;   // v_pk_fma_f32
      ah[j] += nm2 * hf;
    }
  };

  int it = g;
  for (; it + 8 < items; it += 16) {
    int rA = node; float nA = s2;
    if (it > 0) { rA = erow[pe + it - 1]; nA = enorm[pe + it - 1]; }
    int eB = pe + it + 7;
    int rB = erow[eB]; float nB = enorm[eB];
    uint4 xA = X4[(size_t)rA * 64 + soff];
    uint4 hA = H4[(size_t)rA * 64 + soff];
    uint4 xB = X4[(size_t)rB * 64 + soff];
    uint4 hB = H4[(size_t)rB * 64 + soff];
    accum(nA, xA, hA);
    accum(nB, xB, hB);
  }
  if (it < items) {
    int rA = node; float nA = s2;
    if (it > 0) { rA = erow[pe + it - 1]; nA = enorm[pe + it - 1]; }
    accum(nA, X4[(size_t)rA * 64 + soff], H4[(size_t)rA * 64 + soff]);
  }

#pragma unroll
  for (int st = 8; st < 64; st <<= 1) {
#pragma unroll
    for (int j = 0; j < 4; ++j) {
      ax[j].x += __shfl_xor(ax[j].x, st, 64); ax[j].y += __shfl_xor(ax[j].y, st, 64);
      ah[j].x += __shfl_xor(ah[j].x, st, 64); ah[j].y += __shfl_xor(ah[j].y, st, 64);
    }
  }

  if (g == 0) {
    uint4 ox = {bf16pair(ax[0].x, ax[0].y), bf16pair(ax[1].x, ax[1].y),
                bf16pair(ax[2].x, ax[2].y), bf16pair(ax[3].x, ax[3].y)};
    ((uint4*)AXb)[(size_t)node * 64 + soff] = ox;
  } else if (g == 1) {
    uint4 oh = {bf16pair(ah[0].x, ah[0].y), bf16pair(ah[1].x, ah[1].y),
                bf16pair(ah[2].x, ah[2].y), bf16pair(ah[3].x, ah[3].y)};
    ((uint4*)AHb)[(size_t)node * 64 + soff] = oh;
  }
}

__global__ __launch_bounds__(256) void k_agg_single_s2(const u16* __restrict__ Sb,
                                                       const int* __restrict__ ptr,
                                                       const int* __restrict__ erow,
                                                       const float* __restrict__ enorm,
                                                       const float* __restrict__ deg,
                                                       u16* __restrict__ Ab) {
  int bid = blockIdx.x;
  int slice = bid & 7, nb = bid >> 3;
  int w = threadIdx.x >> 6, lane = threadIdx.x & 63;
  int node = nb * 4 + w;
  int g = lane >> 3, cl = lane & 7;
  int soff = slice * 8 + cl;
  const uint4* S4 = (const uint4*)Sb;
  float s = rsqrtf(deg[node]), s2 = s * s;
  int pe = ptr[node];
  int items = ptr[node + 1] - pe + 1;

  f32x2 ax[4] = {};
  auto accum = [&](float nm, uint4 xv) {
    unsigned xw[4] = {xv.x, xv.y, xv.z, xv.w};
    f32x2 nm2 = {nm, nm};
#pragma unroll
    for (int j = 0; j < 4; ++j) {
      f32x2 xf = {bflo(xw[j]), bfhi(xw[j])};
      ax[j] += nm2 * xf;
    }
  };

  int it = g;
  for (; it + 8 < items; it += 16) {
    int rA = node; float nA = s2;
    if (it > 0) { rA = erow[pe + it - 1]; nA = enorm[pe + it - 1]; }
    int eB = pe + it + 7;
    int rB = erow[eB]; float nB = enorm[eB];
    uint4 xA = S4[(size_t)rA * 64 + soff];
    uint4 xB = S4[(size_t)rB * 64 + soff];
    accum(nA, xA);
    accum(nB, xB);
  }
  if (it < items) {
    int rA = node; float nA = s2;
    if (it > 0) { rA = erow[pe + it - 1]; nA = enorm[pe + it - 1]; }
    accum(nA, S4[(size_t)rA * 64 + soff]);
  }

#pragma unroll
  for (int st = 8; st < 64; st <<= 1) {
#pragma unroll
    for (int j = 0; j < 4; ++j) {
      ax[j].x += __shfl_xor(ax[j].x, st, 64); ax[j].y += __shfl_xor(ax[j].y, st, 64);
    }
  }

  if (g == 0) {
    uint4 ox = {bf16pair(ax[0].x, ax[0].y), bf16pair(ax[1].x, ax[1].y),
                bf16pair(ax[2].x, ax[2].y), bf16pair(ax[3].x, ax[3].y)};
    ((uint4*)Ab)[(size_t)node * 64 + soff] = ox;
  }
}

// ---------------- z&r GEMM: 8 col-blocks (z | r), round-9 proven structure ----------
// seg 0 (c 0-3):  Zb  = bf16(sigmoid(AX@Wxz + AH@Whz + bxz+bhz))
// seg 1 (c 4-7):  HRb = bf16(Hb * sigmoid(AX@Wxr + AH@Whr + bxr+bhr))
__global__ __launch_bounds__(256) void k_gemm_big(
    const u16* __restrict__ AXb, const u16* __restrict__ AHb,
    const u16* __restrict__ WtAll,
    const float* __restrict__ bxz, const float* __restrict__ bhz,
    const float* __restrict__ bxr, const float* __restrict__ bhr,
    const u16* __restrict__ Hb,
    u16* __restrict__ Zb, u16* __restrict__ HRb) {
  __shared__ unsigned char smem[32768];
  const int tid = threadIdx.x;
  const int lane = tid & 63, w = tid >> 6;
  const int wr = w >> 1, wc = w & 1;

  // bijective XCD-chunked map over 1256 = 157 row-blocks x 8 col-blocks (1256 = 8*157)
  const int q = 157;
  const int xcd = blockIdx.x & 7, ii = blockIdx.x >> 3;
  const int wk = xcd * q + ii;
  const int rowBase = (wk >> 3) * 128;
  const int c = wk & 7;
  const int seg = c >> 2;
  const int colBase = (c & 3) * 128;

  const u16* W1 = WtAll + (size_t)(seg ? 2 : 0) * 262144;
  const u16* W2 = WtAll + (size_t)(seg ? 3 : 1) * 262144;

  f32x4 acc[4][4] = {};

  const int lrow = lane & 15;
  const int lkb = (lane >> 4) << 4;
  const int swz = (lane & 7) << 4;
  const int srow = w * 32 + (lane >> 3);
  const int scol = (((lane & 7) ^ (lane >> 3)) << 4);

  for (int pass = 0; pass < 2; ++pass) {
    const u16* A = pass ? AHb : AXb;
    const u16* Wt = pass ? W2 : W1;
    const char* Abase = (const char*)A + (size_t)(rowBase + srow) * 1024 + scol;
    const char* Bbase = (const char*)Wt + (size_t)(colBase + srow) * 1024 + scol;
    for (int k0 = 0; k0 < 512; k0 += 64) {
      __syncthreads();
#pragma unroll
      for (int t = 0; t < 4; ++t) {
        gload16(Abase + (size_t)t * 8192 + k0 * 2, &smem[w * 4096 + t * 1024]);
        gload16(Bbase + (size_t)t * 8192 + k0 * 2, &smem[16384 + w * 4096 + t * 1024]);
      }
      __syncthreads();
#pragma unroll
      for (int ks = 0; ks < 2; ++ks) {
        bf16x8 af[4], bfr[4];
#pragma unroll
        for (int fm = 0; fm < 4; ++fm) {
          int row = wr * 64 + fm * 16 + lrow;
          af[fm] = *(const bf16x8*)&smem[row * 128 + (((ks << 6) + lkb) ^ swz)];
        }
#pragma unroll
        for (int fn = 0; fn < 4; ++fn) {
          int row = wc * 64 + fn * 16 + lrow;
          bfr[fn] = *(const bf16x8*)&smem[16384 + row * 128 + (((ks << 6) + lkb) ^ swz)];
        }
#pragma unroll
        for (int fm = 0; fm < 4; ++fm)
#pragma unroll
          for (int fn = 0; fn < 4; ++fn)
            acc[fm][fn] = __builtin_amdgcn_mfma_f32_16x16x32_bf16(af[fm], bfr[fn], acc[fm][fn], 0, 0, 0);
      }
    }
  }
  // epilogue: col=lane&15, row=(lane>>4)*4+reg
#pragma unroll
  for (int fm = 0; fm < 4; ++fm) {
    int rbase = rowBase + wr * 64 + fm * 16 + ((lane >> 4) << 2);
#pragma unroll
    for (int fn = 0; fn < 4; ++fn) {
      int col = colBase + wc * 64 + fn * 16 + lrow;
      float bb = seg ? (bxr[col] + bhr[col]) : (bxz[col] + bhz[col]);
#pragma unroll
      for (int r = 0; r < 4; ++r) {
        int row = rbase + r;
        if (row >= NN) continue;
        size_t idx = (size_t)row * 512 + col;
        float a = acc[fm][fn][r] + bb;
        if (seg == 0) {
          Zb[idx] = bf16one(sigmoidf_(a));
        } else {
          HRb[idx] = bf16one(bf2f(Hb[idx]) * sigmoidf_(a));
        }
      }
    }
  }
}

// ---------------- final GEMM: 2-pass K, out = z*h + (1-z)*tanh(AHR@Whh + AX@Wxh + b) --
__global__ __launch_bounds__(256) void k_gemm_fin(
    const u16* __restrict__ AHRb, const u16* __restrict__ AXb,
    const u16* __restrict__ WtAll,
    const float* __restrict__ bxh, const float* __restrict__ bhh,
    const u16* __restrict__ Hb, const u16* __restrict__ Zb,
    float* __restrict__ out) {
  __shared__ unsigned char smem[32768];
  const int tid = threadIdx.x;
  const int lane = tid & 63, w = tid >> 6;
  const int wr = w >> 1, wc = w & 1;

  const int q = 78, r8 = 4;  // 628 = 8*78+4
  const int xcd = blockIdx.x & 7, ii = blockIdx.x >> 3;
  const int start = (xcd < r8) ? xcd * (q + 1) : r8 * (q + 1) + (xcd - r8) * q;
  const int wk = start + ii;
  const int rowBase = (wk >> 2) * 128;
  const int colBase = (wk & 3) * 128;

  f32x4 acc[4][4] = {};

  const int lrow = lane & 15;
  const int lkb = (lane >> 4) << 4;
  const int swz = (lane & 7) << 4;
  const int srow = w * 32 + (lane >> 3);
  const int scol = (((lane & 7) ^ (lane >> 3)) << 4);

  for (int pass = 0; pass < 2; ++pass) {
    const u16* A  = pass ? AXb : AHRb;
    const u16* Wt = WtAll + (size_t)(pass ? 4 : 5) * 262144;  // Whh then Wxh
    const char* Abase = (const char*)A + (size_t)(rowBase + srow) * 1024 + scol;
    const char* Bbase = (const char*)Wt + (size_t)(colBase + srow) * 1024 + scol;
    for (int k0 = 0; k0 < 512; k0 += 64) {
      __syncthreads();
#pragma unroll
      for (int t = 0; t < 4; ++t) {
        gload16(Abase + (size_t)t * 8192 + k0 * 2, &smem[w * 4096 + t * 1024]);
        gload16(Bbase + (size_t)t * 8192 + k0 * 2, &smem[16384 + w * 4096 + t * 1024]);
      }
      __syncthreads();
#pragma unroll
      for (int ks = 0; ks < 2; ++ks) {
        bf16x8 af[4], bfr[4];
#pragma unroll
        for (int fm = 0; fm < 4; ++fm) {
          int row = wr * 64 + fm * 16 + lrow;
          af[fm] = *(const bf16x8*)&smem[row * 128 + (((ks << 6) + lkb) ^ swz)];
        }
#pragma unroll
        for (int fn = 0; fn < 4; ++fn) {
          int row = wc * 64 + fn * 16 + lrow;
          bfr[fn] = *(const bf16x8*)&smem[16384 + row * 128 + (((ks << 6) + lkb) ^ swz)];
        }
#pragma unroll
        for (int fm = 0; fm < 4; ++fm)
#pragma unroll
          for (int fn = 0; fn < 4; ++fn)
            acc[fm][fn] = __builtin_amdgcn_mfma_f32_16x16x32_bf16(af[fm], bfr[fn], acc[fm][fn], 0, 0, 0);
      }
    }
  }
#pragma unroll
  for (int fm = 0; fm < 4; ++fm) {
    int rbase = rowBase + wr * 64 + fm * 16 + ((lane >> 4) << 2);
#pragma unroll
    for (int fn = 0; fn < 4; ++fn) {
      int col = colBase + wc * 64 + fn * 16 + lrow;
      float bb = bxh[col] + bhh[col];
#pragma unroll
      for (int r = 0; r < 4; ++r) {
        int row = rbase + r;
        if (row >= NN) continue;
        size_t idx = (size_t)row * 512 + col;
        float t = tanhf(acc[fm][fn][r] + bb);
        float z = bf2f(Zb[idx]);
        float h = bf2f(Hb[idx]);
        out[idx] = z * h + (1.f - z) * t;
      }
    }
  }
}

extern "C" void kernel_launch(void* const* d_in, const int* in_sizes, int n_in,
                              void* d_out, int out_size, void* d_ws, size_t ws_size,
                              hipStream_t stream) {
  const float* X   = (const float*)d_in[0];
  const int*   ei  = (const int*)d_in[1];
  const float* ew  = (const float*)d_in[2];
  const float* H   = (const float*)d_in[3];
  const float* Wxz = (const float*)d_in[4];  const float* bxz = (const float*)d_in[5];
  const float* Whz = (const float*)d_in[6];  const float* bhz = (const float*)d_in[7];
  const float* Wxr = (const float*)d_in[8];  const float* bxr = (const float*)d_in[9];
  const float* Whr = (const float*)d_in[10]; const float* bhr = (const float*)d_in[11];
  const float* Wxh = (const float*)d_in[12]; const float* bxh = (const float*)d_in[13];
  const float* Whh = (const float*)d_in[14]; const float* bhh = (const float*)d_in[15];
  const int* row = ei;
  const int* col = ei + NE;
  float* out = (float*)d_out;

  char* base = (char*)d_ws;
  size_t o = 0;
  auto alloc = [&](size_t b) { char* p = base + o; o += (b + 255) & ~(size_t)255; return p; };
  u16* Xb   = (u16*)alloc((size_t)NP * DD * 2);  // aliases AHRb (Xb dead after agg_dual)
  u16* Hb   = (u16*)alloc((size_t)NP * DD * 2);  // live through gemm_fin epilogue
  u16* AXb  = (u16*)alloc((size_t)NP * DD * 2);  // live through gemm_fin pass 2
  u16* AHb  = (u16*)alloc((size_t)NP * DD * 2);
  u16* HRb  = (u16*)alloc((size_t)NP * DD * 2);
  u16* Zb   = (u16*)alloc((size_t)NP * DD * 2);
  u16* WtAll= (u16*)alloc((size_t)6 * 512 * 512 * 2);
  float* deg  = (float*)alloc(NN * 4);
  int*   cnt  = (int*)alloc(NN * 4);
  int*   ptr  = (int*)alloc((NN + 1) * 4);
  int*   pos  = (int*)alloc(NN * 4);
  int*   erow = (int*)alloc(NE * 4);
  float* enorm= (float*)alloc(NE * 4);
  u16* AHRb = Xb;   // Xb dead after k_agg_dual_s2

  dim3 b256(256);
  int gE = (NE + 255) / 256;

  // fused setup: cvt X/H -> bf16 | init deg/cnt | 6 weight transposes
  k_setup<<<CVT_B + INIT_B + WT_B, b256, 0, stream>>>(
      X, H, Xb, Hb, Wxz, Whz, Wxr, Whr, Wxh, Whh, WtAll, deg, cnt);

  // CSR build
  k_accum<<<gE, b256, 0, stream>>>(col, ew, deg, cnt);
  k_scan<<<1, 1024, 0, stream>>>(cnt, ptr, pos);
  k_scatter<<<gE, b256, 0, stream>>>(row, col, ew, deg, pos, erow, enorm);

  // AX = Agg(X), AH = Agg(H)
  k_agg_dual_s2<<<40000, b256, 0, stream>>>(Xb, Hb, ptr, erow, enorm, deg, AXb, AHb);

  // z & r GEMM -> Zb, HRb
  k_gemm_big<<<1256, b256, 0, stream>>>(AXb, AHb, WtAll, bxz, bhz, bxr, bhr,
                                        Hb, Zb, HRb);

  // AHR = Agg(HR)
  k_agg_single_s2<<<40000, b256, 0, stream>>>(HRb, ptr, erow, enorm, deg, AHRb);

  // out = z*h + (1-z)*tanh(AHR@Whh + AX@Wxh + bxh + bhh)
  k_gemm_fin<<<628, b256, 0, stream>>>(AHRb, AXb, WtAll, bxh, bhh,
                                       Hb, Zb, out);
}

// Round 13
// 339.536 us; speedup vs baseline: 1.3461x; 1.1341x over previous
//
#include <hip/hip_runtime.h>

#define NN 20000
#define NP 20096   // padded rows (multiple of 128)
#define NE 320000
#define DD 512

typedef __bf16 bf16x8 __attribute__((ext_vector_type(8)));
typedef float f32x4 __attribute__((ext_vector_type(4)));
typedef float f32x2 __attribute__((ext_vector_type(2)));
typedef unsigned short u16;

__device__ __forceinline__ float sigmoidf_(float x) { return 1.f / (1.f + expf(-x)); }

__device__ __forceinline__ unsigned bf16pair(float a, float b) {
  unsigned ua = __builtin_bit_cast(unsigned, a);
  unsigned ub = __builtin_bit_cast(unsigned, b);
  ua = (ua + 0x7FFFu + ((ua >> 16) & 1u)) >> 16;
  ub = (ub + 0x7FFFu + ((ub >> 16) & 1u)) >> 16;
  return ua | (ub << 16);
}
__device__ __forceinline__ u16 bf16one(float a) {
  unsigned ua = __builtin_bit_cast(unsigned, a);
  return (u16)((ua + 0x7FFFu + ((ua >> 16) & 1u)) >> 16);
}
__device__ __forceinline__ float bflo(unsigned w) { return __builtin_bit_cast(float, w << 16); }
__device__ __forceinline__ float bfhi(unsigned w) { return __builtin_bit_cast(float, w & 0xFFFF0000u); }
__device__ __forceinline__ float bf2f(u16 v) { return __builtin_bit_cast(float, (unsigned)v << 16); }

__device__ __forceinline__ void gload16(const void* g, void* l) {
  __builtin_amdgcn_global_load_lds(
      (const __attribute__((address_space(1))) unsigned int*)g,
      (__attribute__((address_space(3))) unsigned int*)l, 16, 0, 0);
}

// ---------------- fused setup: cvt(X,H)->bf16 | init deg/cnt | 6 weight transposes ----
#define CVT_B 10000   // 2*NN*DD/8/256
#define INIT_B 79     // ceil(NN/256)
#define WT_B 1536     // 6 * 16 * 16
__global__ __launch_bounds__(256) void k_setup(
    const float* __restrict__ X, const float* __restrict__ H,
    u16* __restrict__ Xb, u16* __restrict__ Hb,
    const float* __restrict__ W0, const float* __restrict__ W1,
    const float* __restrict__ W2, const float* __restrict__ W3,
    const float* __restrict__ W4, const float* __restrict__ W5,
    u16* __restrict__ T, float* __restrict__ deg, int* __restrict__ cnt) {
  __shared__ float t[32][33];
  int b = blockIdx.x;
  if (b < CVT_B) {
    const int n8 = NN * DD / 8;
    int i = b * 256 + threadIdx.x;
    const float* src = (i < n8) ? X : H;
    u16* dst = (i < n8) ? Xb : Hb;
    int k = (i < n8) ? i : i - n8;
    const float4* s = (const float4*)src;
    float4 v0 = s[k * 2], v1 = s[k * 2 + 1];
    uint4 o = {bf16pair(v0.x, v0.y), bf16pair(v0.z, v0.w),
               bf16pair(v1.x, v1.y), bf16pair(v1.z, v1.w)};
    ((uint4*)dst)[k] = o;
  } else if (b < CVT_B + INIT_B) {
    int i = (b - CVT_B) * 256 + threadIdx.x;
    if (i < NN) { deg[i] = 1.0f; cnt[i] = 0; }
  } else {
    int wb = b - CVT_B - INIT_B;          // [0, 1536)
    const float* Wsrc;
    switch (wb >> 8) {
      case 0: Wsrc = W0; break; case 1: Wsrc = W1; break; case 2: Wsrc = W2; break;
      case 3: Wsrc = W3; break; case 4: Wsrc = W4; break; default: Wsrc = W5; break;
    }
    u16* Wt = T + (size_t)(wb >> 8) * 262144;
    int rb = wb & 255;
    int kb = (rb & 15) * 32, nb = (rb >> 4) * 32;
    int tx = threadIdx.x & 31, ty = threadIdx.x >> 5;
#pragma unroll
    for (int i2 = 0; i2 < 4; ++i2)
      t[ty * 4 + i2][tx] = Wsrc[(size_t)(kb + ty * 4 + i2) * 512 + nb + tx];
    __syncthreads();
#pragma unroll
    for (int i2 = 0; i2 < 4; ++i2)
      Wt[(size_t)(nb + ty * 4 + i2) * 512 + kb + tx] = bf16one(t[tx][ty * 4 + i2]);
  }
}

// ---------------- degree / CSR ----------------
__global__ void k_accum(const int* col, const float* w, float* deg, int* cnt) {
  int e = blockIdx.x * 256 + threadIdx.x;
  if (e < NE) {
    int c = col[e];
    atomicAdd(&deg[c], w[e]);
    atomicAdd(&cnt[c], 1);
  }
}

__global__ void k_scan(const int* cnt, int* ptr, int* pos) {
  __shared__ int sdata[1024];
  const int ITEMS = (NN + 1023) / 1024;
  int tid = threadIdx.x;
  int base = tid * ITEMS;
  int s = 0;
  for (int j = 0; j < ITEMS; ++j) { int i = base + j; if (i < NN) s += cnt[i]; }
  sdata[tid] = s;
  __syncthreads();
  for (int off = 1; off < 1024; off <<= 1) {
    int v = 0;
    if (tid >= off) v = sdata[tid - off];
    __syncthreads();
    sdata[tid] += v;
    __syncthreads();
  }
  int run = (tid == 0) ? 0 : sdata[tid - 1];
  for (int j = 0; j < ITEMS; ++j) {
    int i = base + j;
    if (i < NN) { ptr[i] = run; pos[i] = run; run += cnt[i]; }
  }
  if (tid == 0) ptr[NN] = NE;
}

__global__ void k_scatter(const int* row, const int* col, const float* w, const float* deg,
                          int* pos, int* erow, float* enorm) {
  int e = blockIdx.x * 256 + threadIdx.x;
  if (e < NE) {
    int r = row[e], c = col[e];
    int slot = atomicAdd(&pos[c], 1);
    erow[slot] = r;
    enorm[slot] = rsqrtf(deg[r]) * w[e] * rsqrtf(deg[c]);
  }
}

// ---------------- XCD-sliced aggregation: 4 nodes/wave, 2 item-groups, 1-stage tail ----
// slice = bid&7; block = 4 waves = 16 nodes (20000 = 1250*16 exact).
// quarter (16 lanes) = one node; within quarter: group g in {0,1} of 8 lanes x 16B.
// group g handles items g, g+2, g+4, ... (unroll-2). item 0 = self-loop (dinv^2).
// Tail: ONE shfl_xor stage (stride 8) within the quarter.
__global__ __launch_bounds__(256) void k_agg_dual_s3(const u16* __restrict__ Xb,
                                                     const u16* __restrict__ Hb,
                                                     const int* __restrict__ ptr,
                                                     const int* __restrict__ erow,
                                                     const float* __restrict__ enorm,
                                                     const float* __restrict__ deg,
                                                     u16* __restrict__ AXb,
                                                     u16* __restrict__ AHb) {
  int bid = blockIdx.x;
  int slice = bid & 7, nb = bid >> 3;
  int w = threadIdx.x >> 6, lane = threadIdx.x & 63;
  int node = nb * 16 + w * 4 + (lane >> 4);
  int q = lane & 15;
  int g = q >> 3, cl = q & 7;
  int soff = slice * 8 + cl;                 // uint4 index within a 64-uint4 row
  const uint4* X4 = (const uint4*)Xb;
  const uint4* H4 = (const uint4*)Hb;
  float s = rsqrtf(deg[node]), s2 = s * s;
  int pe = ptr[node];
  int items = ptr[node + 1] - pe + 1;        // self + deg

  f32x2 ax[4] = {}, ah[4] = {};
  auto accum = [&](float nm, uint4 xv, uint4 hv) {
    unsigned xw[4] = {xv.x, xv.y, xv.z, xv.w};
    unsigned hw[4] = {hv.x, hv.y, hv.z, hv.w};
    f32x2 nm2 = {nm, nm};
#pragma unroll
    for (int j = 0; j < 4; ++j) {
      f32x2 xf = {bflo(xw[j]), bfhi(xw[j])};
      f32x2 hf = {bflo(hw[j]), bfhi(hw[j])};
      ax[j] += nm2 * xf;   // v_pk_fma_f32
      ah[j] += nm2 * hf;
    }
  };

  int it = g;
  for (; it + 2 < items; it += 4) {
    int rA = node; float nA = s2;
    if (it > 0) { rA = erow[pe + it - 1]; nA = enorm[pe + it - 1]; }
    int eB = pe + it + 1;                    // item it+2 -> edge pe+it+1
    int rB = erow[eB]; float nB = enorm[eB];
    uint4 xA = X4[(size_t)rA * 64 + soff];
    uint4 hA = H4[(size_t)rA * 64 + soff];
    uint4 xB = X4[(size_t)rB * 64 + soff];
    uint4 hB = H4[(size_t)rB * 64 + soff];
    accum(nA, xA, hA);
    accum(nB, xB, hB);
  }
  if (it < items) {
    int rA = node; float nA = s2;
    if (it > 0) { rA = erow[pe + it - 1]; nA = enorm[pe + it - 1]; }
    accum(nA, X4[(size_t)rA * 64 + soff], H4[(size_t)rA * 64 + soff]);
  }

  // single butterfly stage: combine the quarter's two groups
#pragma unroll
  for (int j = 0; j < 4; ++j) {
    ax[j].x += __shfl_xor(ax[j].x, 8, 64); ax[j].y += __shfl_xor(ax[j].y, 8, 64);
    ah[j].x += __shfl_xor(ah[j].x, 8, 64); ah[j].y += __shfl_xor(ah[j].y, 8, 64);
  }

  if (g == 0) {
    uint4 ox = {bf16pair(ax[0].x, ax[0].y), bf16pair(ax[1].x, ax[1].y),
                bf16pair(ax[2].x, ax[2].y), bf16pair(ax[3].x, ax[3].y)};
    ((uint4*)AXb)[(size_t)node * 64 + soff] = ox;
  } else {
    uint4 oh = {bf16pair(ah[0].x, ah[0].y), bf16pair(ah[1].x, ah[1].y),
                bf16pair(ah[2].x, ah[2].y), bf16pair(ah[3].x, ah[3].y)};
    ((uint4*)AHb)[(size_t)node * 64 + soff] = oh;
  }
}

__global__ __launch_bounds__(256) void k_agg_single_s3(const u16* __restrict__ Sb,
                                                       const int* __restrict__ ptr,
                                                       const int* __restrict__ erow,
                                                       const float* __restrict__ enorm,
                                                       const float* __restrict__ deg,
                                                       u16* __restrict__ Ab) {
  int bid = blockIdx.x;
  int slice = bid & 7, nb = bid >> 3;
  int w = threadIdx.x >> 6, lane = threadIdx.x & 63;
  int node = nb * 16 + w * 4 + (lane >> 4);
  int q = lane & 15;
  int g = q >> 3, cl = q & 7;
  int soff = slice * 8 + cl;
  const uint4* S4 = (const uint4*)Sb;
  float s = rsqrtf(deg[node]), s2 = s * s;
  int pe = ptr[node];
  int items = ptr[node + 1] - pe + 1;

  f32x2 ax[4] = {};
  auto accum = [&](float nm, uint4 xv) {
    unsigned xw[4] = {xv.x, xv.y, xv.z, xv.w};
    f32x2 nm2 = {nm, nm};
#pragma unroll
    for (int j = 0; j < 4; ++j) {
      f32x2 xf = {bflo(xw[j]), bfhi(xw[j])};
      ax[j] += nm2 * xf;
    }
  };

  int it = g;
  for (; it + 2 < items; it += 4) {
    int rA = node; float nA = s2;
    if (it > 0) { rA = erow[pe + it - 1]; nA = enorm[pe + it - 1]; }
    int eB = pe + it + 1;
    int rB = erow[eB]; float nB = enorm[eB];
    uint4 xA = S4[(size_t)rA * 64 + soff];
    uint4 xB = S4[(size_t)rB * 64 + soff];
    accum(nA, xA);
    accum(nB, xB);
  }
  if (it < items) {
    int rA = node; float nA = s2;
    if (it > 0) { rA = erow[pe + it - 1]; nA = enorm[pe + it - 1]; }
    accum(nA, S4[(size_t)rA * 64 + soff]);
  }

#pragma unroll
  for (int j = 0; j < 4; ++j) {
    ax[j].x += __shfl_xor(ax[j].x, 8, 64); ax[j].y += __shfl_xor(ax[j].y, 8, 64);
  }

  if (g == 0) {
    uint4 ox = {bf16pair(ax[0].x, ax[0].y), bf16pair(ax[1].x, ax[1].y),
                bf16pair(ax[2].x, ax[2].y), bf16pair(ax[3].x, ax[3].y)};
    ((uint4*)Ab)[(size_t)node * 64 + soff] = ox;
  }
}

// ---------------- z&r GEMM: 8 col-blocks (z | r), round-9 proven structure ----------
// seg 0 (c 0-3):  Zb  = bf16(sigmoid(AX@Wxz + AH@Whz + bxz+bhz))
// seg 1 (c 4-7):  HRb = bf16(Hb * sigmoid(AX@Wxr + AH@Whr + bxr+bhr))
__global__ __launch_bounds__(256) void k_gemm_big(
    const u16* __restrict__ AXb, const u16* __restrict__ AHb,
    const u16* __restrict__ WtAll,
    const float* __restrict__ bxz, const float* __restrict__ bhz,
    const float* __restrict__ bxr, const float* __restrict__ bhr,
    const u16* __restrict__ Hb,
    u16* __restrict__ Zb, u16* __restrict__ HRb) {
  __shared__ unsigned char smem[32768];
  const int tid = threadIdx.x;
  const int lane = tid & 63, w = tid >> 6;
  const int wr = w >> 1, wc = w & 1;

  // bijective XCD-chunked map over 1256 = 157 row-blocks x 8 col-blocks (1256 = 8*157)
  const int q = 157;
  const int xcd = blockIdx.x & 7, ii = blockIdx.x >> 3;
  const int wk = xcd * q + ii;
  const int rowBase = (wk >> 3) * 128;
  const int c = wk & 7;
  const int seg = c >> 2;
  const int colBase = (c & 3) * 128;

  const u16* W1 = WtAll + (size_t)(seg ? 2 : 0) * 262144;
  const u16* W2 = WtAll + (size_t)(seg ? 3 : 1) * 262144;

  f32x4 acc[4][4] = {};

  const int lrow = lane & 15;
  const int lkb = (lane >> 4) << 4;
  const int swz = (lane & 7) << 4;
  const int srow = w * 32 + (lane >> 3);
  const int scol = (((lane & 7) ^ (lane >> 3)) << 4);

  for (int pass = 0; pass < 2; ++pass) {
    const u16* A = pass ? AHb : AXb;
    const u16* Wt = pass ? W2 : W1;
    const char* Abase = (const char*)A + (size_t)(rowBase + srow) * 1024 + scol;
    const char* Bbase = (const char*)Wt + (size_t)(colBase + srow) * 1024 + scol;
    for (int k0 = 0; k0 < 512; k0 += 64) {
      __syncthreads();
#pragma unroll
      for (int t = 0; t < 4; ++t) {
        gload16(Abase + (size_t)t * 8192 + k0 * 2, &smem[w * 4096 + t * 1024]);
        gload16(Bbase + (size_t)t * 8192 + k0 * 2, &smem[16384 + w * 4096 + t * 1024]);
      }
      __syncthreads();
#pragma unroll
      for (int ks = 0; ks < 2; ++ks) {
        bf16x8 af[4], bfr[4];
#pragma unroll
        for (int fm = 0; fm < 4; ++fm) {
          int row = wr * 64 + fm * 16 + lrow;
          af[fm] = *(const bf16x8*)&smem[row * 128 + (((ks << 6) + lkb) ^ swz)];
        }
#pragma unroll
        for (int fn = 0; fn < 4; ++fn) {
          int row = wc * 64 + fn * 16 + lrow;
          bfr[fn] = *(const bf16x8*)&smem[16384 + row * 128 + (((ks << 6) + lkb) ^ swz)];
        }
#pragma unroll
        for (int fm = 0; fm < 4; ++fm)
#pragma unroll
          for (int fn = 0; fn < 4; ++fn)
            acc[fm][fn] = __builtin_amdgcn_mfma_f32_16x16x32_bf16(af[fm], bfr[fn], acc[fm][fn], 0, 0, 0);
      }
    }
  }
  // epilogue: col=lane&15, row=(lane>>4)*4+reg
#pragma unroll
  for (int fm = 0; fm < 4; ++fm) {
    int rbase = rowBase + wr * 64 + fm * 16 + ((lane >> 4) << 2);
#pragma unroll
    for (int fn = 0; fn < 4; ++fn) {
      int col = colBase + wc * 64 + fn * 16 + lrow;
      float bb = seg ? (bxr[col] + bhr[col]) : (bxz[col] + bhz[col]);
#pragma unroll
      for (int r = 0; r < 4; ++r) {
        int row = rbase + r;
        if (row >= NN) continue;
        size_t idx = (size_t)row * 512 + col;
        float a = acc[fm][fn][r] + bb;
        if (seg == 0) {
          Zb[idx] = bf16one(sigmoidf_(a));
        } else {
          HRb[idx] = bf16one(bf2f(Hb[idx]) * sigmoidf_(a));
        }
      }
    }
  }
}

// ---------------- final GEMM: 2-pass K, out = z*h + (1-z)*tanh(AHR@Whh + AX@Wxh + b) --
__global__ __launch_bounds__(256) void k_gemm_fin(
    const u16* __restrict__ AHRb, const u16* __restrict__ AXb,
    const u16* __restrict__ WtAll,
    const float* __restrict__ bxh, const float* __restrict__ bhh,
    const u16* __restrict__ Hb, const u16* __restrict__ Zb,
    float* __restrict__ out) {
  __shared__ unsigned char smem[32768];
  const int tid = threadIdx.x;
  const int lane = tid & 63, w = tid >> 6;
  const int wr = w >> 1, wc = w & 1;

  const int q = 78, r8 = 4;  // 628 = 8*78+4
  const int xcd = blockIdx.x & 7, ii = blockIdx.x >> 3;
  const int start = (xcd < r8) ? xcd * (q + 1) : r8 * (q + 1) + (xcd - r8) * q;
  const int wk = start + ii;
  const int rowBase = (wk >> 2) * 128;
  const int colBase = (wk & 3) * 128;

  f32x4 acc[4][4] = {};

  const int lrow = lane & 15;
  const int lkb = (lane >> 4) << 4;
  const int swz = (lane & 7) << 4;
  const int srow = w * 32 + (lane >> 3);
  const int scol = (((lane & 7) ^ (lane >> 3)) << 4);

  for (int pass = 0; pass < 2; ++pass) {
    const u16* A  = pass ? AXb : AHRb;
    const u16* Wt = WtAll + (size_t)(pass ? 4 : 5) * 262144;  // Whh then Wxh
    const char* Abase = (const char*)A + (size_t)(rowBase + srow) * 1024 + scol;
    const char* Bbase = (const char*)Wt + (size_t)(colBase + srow) * 1024 + scol;
    for (int k0 = 0; k0 < 512; k0 += 64) {
      __syncthreads();
#pragma unroll
      for (int t = 0; t < 4; ++t) {
        gload16(Abase + (size_t)t * 8192 + k0 * 2, &smem[w * 4096 + t * 1024]);
        gload16(Bbase + (size_t)t * 8192 + k0 * 2, &smem[16384 + w * 4096 + t * 1024]);
      }
      __syncthreads();
#pragma unroll
      for (int ks = 0; ks < 2; ++ks) {
        bf16x8 af[4], bfr[4];
#pragma unroll
        for (int fm = 0; fm < 4; ++fm) {
          int row = wr * 64 + fm * 16 + lrow;
          af[fm] = *(const bf16x8*)&smem[row * 128 + (((ks << 6) + lkb) ^ swz)];
        }
#pragma unroll
        for (int fn = 0; fn < 4; ++fn) {
          int row = wc * 64 + fn * 16 + lrow;
          bfr[fn] = *(const bf16x8*)&smem[16384 + row * 128 + (((ks << 6) + lkb) ^ swz)];
        }
#pragma unroll
        for (int fm = 0; fm < 4; ++fm)
#pragma unroll
          for (int fn = 0; fn < 4; ++fn)
            acc[fm][fn] = __builtin_amdgcn_mfma_f32_16x16x32_bf16(af[fm], bfr[fn], acc[fm][fn], 0, 0, 0);
      }
    }
  }
#pragma unroll
  for (int fm = 0; fm < 4; ++fm) {
    int rbase = rowBase + wr * 64 + fm * 16 + ((lane >> 4) << 2);
#pragma unroll
    for (int fn = 0; fn < 4; ++fn) {
      int col = colBase + wc * 64 + fn * 16 + lrow;
      float bb = bxh[col] + bhh[col];
#pragma unroll
      for (int r = 0; r < 4; ++r) {
        int row = rbase + r;
        if (row >= NN) continue;
        size_t idx = (size_t)row * 512 + col;
        float t = tanhf(acc[fm][fn][r] + bb);
        float z = bf2f(Zb[idx]);
        float h = bf2f(Hb[idx]);
        out[idx] = z * h + (1.f - z) * t;
      }
    }
  }
}

extern "C" void kernel_launch(void* const* d_in, const int* in_sizes, int n_in,
                              void* d_out, int out_size, void* d_ws, size_t ws_size,
                              hipStream_t stream) {
  const float* X   = (const float*)d_in[0];
  const int*   ei  = (const int*)d_in[1];
  const float* ew  = (const float*)d_in[2];
  const float* H   = (const float*)d_in[3];
  const float* Wxz = (const float*)d_in[4];  const float* bxz = (const float*)d_in[5];
  const float* Whz = (const float*)d_in[6];  const float* bhz = (const float*)d_in[7];
  const float* Wxr = (const float*)d_in[8];  const float* bxr = (const float*)d_in[9];
  const float* Whr = (const float*)d_in[10]; const float* bhr = (const float*)d_in[11];
  const float* Wxh = (const float*)d_in[12]; const float* bxh = (const float*)d_in[13];
  const float* Whh = (const float*)d_in[14]; const float* bhh = (const float*)d_in[15];
  const int* row = ei;
  const int* col = ei + NE;
  float* out = (float*)d_out;

  char* base = (char*)d_ws;
  size_t o = 0;
  auto alloc = [&](size_t b) { char* p = base + o; o += (b + 255) & ~(size_t)255; return p; };
  u16* Xb   = (u16*)alloc((size_t)NP * DD * 2);  // aliases AHRb (Xb dead after agg_dual)
  u16* Hb   = (u16*)alloc((size_t)NP * DD * 2);  // live through gemm_fin epilogue
  u16* AXb  = (u16*)alloc((size_t)NP * DD * 2);  // live through gemm_fin pass 2
  u16* AHb  = (u16*)alloc((size_t)NP * DD * 2);
  u16* HRb  = (u16*)alloc((size_t)NP * DD * 2);
  u16* Zb   = (u16*)alloc((size_t)NP * DD * 2);
  u16* WtAll= (u16*)alloc((size_t)6 * 512 * 512 * 2);
  float* deg  = (float*)alloc(NN * 4);
  int*   cnt  = (int*)alloc(NN * 4);
  int*   ptr  = (int*)alloc((NN + 1) * 4);
  int*   pos  = (int*)alloc(NN * 4);
  int*   erow = (int*)alloc(NE * 4);
  float* enorm= (float*)alloc(NE * 4);
  u16* AHRb = Xb;   // Xb dead after k_agg_dual_s3

  dim3 b256(256);
  int gE = (NE + 255) / 256;

  // fused setup: cvt X/H -> bf16 | init deg/cnt | 6 weight transposes
  k_setup<<<CVT_B + INIT_B + WT_B, b256, 0, stream>>>(
      X, H, Xb, Hb, Wxz, Whz, Wxr, Whr, Wxh, Whh, WtAll, deg, cnt);

  // CSR build
  k_accum<<<gE, b256, 0, stream>>>(col, ew, deg, cnt);
  k_scan<<<1, 1024, 0, stream>>>(cnt, ptr, pos);
  k_scatter<<<gE, b256, 0, stream>>>(row, col, ew, deg, pos, erow, enorm);

  // AX = Agg(X), AH = Agg(H): 4 nodes/wave, 2 item-groups, 1-stage tail
  k_agg_dual_s3<<<10000, b256, 0, stream>>>(Xb, Hb, ptr, erow, enorm, deg, AXb, AHb);

  // z & r GEMM -> Zb, HRb
  k_gemm_big<<<1256, b256, 0, stream>>>(AXb, AHb, WtAll, bxz, bhz, bxr, bhr,
                                        Hb, Zb, HRb);

  // AHR = Agg(HR)
  k_agg_single_s3<<<10000, b256, 0, stream>>>(HRb, ptr, erow, enorm, deg, AHRb);

  // out = z*h + (1-z)*tanh(AHR@Whh + AX@Wxh + bxh + bhh)
  k_gemm_fin<<<628, b256, 0, stream>>>(AHRb, AXb, WtAll, bxh, bhh,
                                       Hb, Zb, out);
}

// Round 14
// 327.169 us; speedup vs baseline: 1.3970x; 1.0378x over previous
//
#include <hip/hip_runtime.h>

#define NN 20000
#define NP 20096   // padded rows (multiple of 128)
#define NE 320000
#define DD 512

typedef __bf16 bf16x8 __attribute__((ext_vector_type(8)));
typedef float f32x4 __attribute__((ext_vector_type(4)));
typedef float f32x2 __attribute__((ext_vector_type(2)));
typedef unsigned short u16;

// fast transcendentals: v_exp_f32 + v_rcp_f32, branchless
__device__ __forceinline__ float sigmoidf_(float x) {
  return __builtin_amdgcn_rcpf(1.f + __expf(-x));
}
__device__ __forceinline__ float tanhf_(float x) {
  float xc = fminf(fmaxf(x, -15.f), 15.f);
  float u = __expf(2.f * xc);
  return (u - 1.f) * __builtin_amdgcn_rcpf(u + 1.f);
}

__device__ __forceinline__ unsigned bf16pair(float a, float b) {
  unsigned ua = __builtin_bit_cast(unsigned, a);
  unsigned ub = __builtin_bit_cast(unsigned, b);
  ua = (ua + 0x7FFFu + ((ua >> 16) & 1u)) >> 16;
  ub = (ub + 0x7FFFu + ((ub >> 16) & 1u)) >> 16;
  return ua | (ub << 16);
}
__device__ __forceinline__ u16 bf16one(float a) {
  unsigned ua = __builtin_bit_cast(unsigned, a);
  return (u16)((ua + 0x7FFFu + ((ua >> 16) & 1u)) >> 16);
}
__device__ __forceinline__ float bflo(unsigned w) { return __builtin_bit_cast(float, w << 16); }
__device__ __forceinline__ float bfhi(unsigned w) { return __builtin_bit_cast(float, w & 0xFFFF0000u); }
__device__ __forceinline__ float bf2f(u16 v) { return __builtin_bit_cast(float, (unsigned)v << 16); }

__device__ __forceinline__ void gload16(const void* g, void* l) {
  __builtin_amdgcn_global_load_lds(
      (const __attribute__((address_space(1))) unsigned int*)g,
      (__attribute__((address_space(3))) unsigned int*)l, 16, 0, 0);
}

// ---------------- fused setup: cvt(X,H)->bf16 | init deg/cnt | 6 weight transposes ----
#define CVT_B 10000   // 2*NN*DD/8/256
#define INIT_B 79     // ceil(NN/256)
#define WT_B 1536     // 6 * 16 * 16
__global__ __launch_bounds__(256) void k_setup(
    const float* __restrict__ X, const float* __restrict__ H,
    u16* __restrict__ Xb, u16* __restrict__ Hb,
    const float* __restrict__ W0, const float* __restrict__ W1,
    const float* __restrict__ W2, const float* __restrict__ W3,
    const float* __restrict__ W4, const float* __restrict__ W5,
    u16* __restrict__ T, float* __restrict__ deg, int* __restrict__ cnt) {
  __shared__ float t[32][33];
  int b = blockIdx.x;
  if (b < CVT_B) {
    const int n8 = NN * DD / 8;
    int i = b * 256 + threadIdx.x;
    const float* src = (i < n8) ? X : H;
    u16* dst = (i < n8) ? Xb : Hb;
    int k = (i < n8) ? i : i - n8;
    const float4* s = (const float4*)src;
    float4 v0 = s[k * 2], v1 = s[k * 2 + 1];
    uint4 o = {bf16pair(v0.x, v0.y), bf16pair(v0.z, v0.w),
               bf16pair(v1.x, v1.y), bf16pair(v1.z, v1.w)};
    ((uint4*)dst)[k] = o;
  } else if (b < CVT_B + INIT_B) {
    int i = (b - CVT_B) * 256 + threadIdx.x;
    if (i < NN) { deg[i] = 1.0f; cnt[i] = 0; }
  } else {
    int wb = b - CVT_B - INIT_B;          // [0, 1536)
    const float* Wsrc;
    switch (wb >> 8) {
      case 0: Wsrc = W0; break; case 1: Wsrc = W1; break; case 2: Wsrc = W2; break;
      case 3: Wsrc = W3; break; case 4: Wsrc = W4; break; default: Wsrc = W5; break;
    }
    u16* Wt = T + (size_t)(wb >> 8) * 262144;
    int rb = wb & 255;
    int kb = (rb & 15) * 32, nb = (rb >> 4) * 32;
    int tx = threadIdx.x & 31, ty = threadIdx.x >> 5;
#pragma unroll
    for (int i2 = 0; i2 < 4; ++i2)
      t[ty * 4 + i2][tx] = Wsrc[(size_t)(kb + ty * 4 + i2) * 512 + nb + tx];
    __syncthreads();
#pragma unroll
    for (int i2 = 0; i2 < 4; ++i2)
      Wt[(size_t)(nb + ty * 4 + i2) * 512 + kb + tx] = bf16one(t[tx][ty * 4 + i2]);
  }
}

// ---------------- degree / CSR ----------------
__global__ void k_accum(const int* col, const float* w, float* deg, int* cnt) {
  int e = blockIdx.x * 256 + threadIdx.x;
  if (e < NE) {
    int c = col[e];
    atomicAdd(&deg[c], w[e]);
    atomicAdd(&cnt[c], 1);
  }
}

__global__ void k_scan(const int* cnt, int* ptr, int* pos) {
  __shared__ int sdata[1024];
  const int ITEMS = (NN + 1023) / 1024;
  int tid = threadIdx.x;
  int base = tid * ITEMS;
  int s = 0;
  for (int j = 0; j < ITEMS; ++j) { int i = base + j; if (i < NN) s += cnt[i]; }
  sdata[tid] = s;
  __syncthreads();
  for (int off = 1; off < 1024; off <<= 1) {
    int v = 0;
    if (tid >= off) v = sdata[tid - off];
    __syncthreads();
    sdata[tid] += v;
    __syncthreads();
  }
  int run = (tid == 0) ? 0 : sdata[tid - 1];
  for (int j = 0; j < ITEMS; ++j) {
    int i = base + j;
    if (i < NN) { ptr[i] = run; pos[i] = run; run += cnt[i]; }
  }
  if (tid == 0) ptr[NN] = NE;
}

__global__ void k_scatter(const int* row, const int* col, const float* w, const float* deg,
                          int* pos, int* erow, float* enorm) {
  int e = blockIdx.x * 256 + threadIdx.x;
  if (e < NE) {
    int r = row[e], c = col[e];
    int slot = atomicAdd(&pos[c], 1);
    erow[slot] = r;
    enorm[slot] = rsqrtf(deg[r]) * w[e] * rsqrtf(deg[c]);
  }
}

// ---------------- XCD-sliced aggregation: 4 nodes/wave, 2 item-groups, unroll-4 ----
// slice = bid&7; quarter (16 lanes) = one node; group g in {0,1} handles items
// g, g+2, g+4, ... (stride 2). unroll-4: 4 items (16 gathers dual) in flight.
// item 0 = self-loop (dinv^2). Tail: ONE shfl_xor stage (stride 8).
__global__ __launch_bounds__(256) void k_agg_dual_s3(const u16* __restrict__ Xb,
                                                     const u16* __restrict__ Hb,
                                                     const int* __restrict__ ptr,
                                                     const int* __restrict__ erow,
                                                     const float* __restrict__ enorm,
                                                     const float* __restrict__ deg,
                                                     u16* __restrict__ AXb,
                                                     u16* __restrict__ AHb) {
  int bid = blockIdx.x;
  int slice = bid & 7, nb = bid >> 3;
  int w = threadIdx.x >> 6, lane = threadIdx.x & 63;
  int node = nb * 16 + w * 4 + (lane >> 4);
  int q = lane & 15;
  int g = q >> 3, cl = q & 7;
  int soff = slice * 8 + cl;                 // uint4 index within a 64-uint4 row
  const uint4* X4 = (const uint4*)Xb;
  const uint4* H4 = (const uint4*)Hb;
  float s = rsqrtf(deg[node]), s2 = s * s;
  int pe = ptr[node];
  int items = ptr[node + 1] - pe + 1;        // self + deg

  f32x2 ax[4] = {}, ah[4] = {};
  auto accum = [&](float nm, uint4 xv, uint4 hv) {
    unsigned xw[4] = {xv.x, xv.y, xv.z, xv.w};
    unsigned hw[4] = {hv.x, hv.y, hv.z, hv.w};
    f32x2 nm2 = {nm, nm};
#pragma unroll
    for (int j = 0; j < 4; ++j) {
      f32x2 xf = {bflo(xw[j]), bfhi(xw[j])};
      f32x2 hf = {bflo(hw[j]), bfhi(hw[j])};
      ax[j] += nm2 * xf;   // v_pk_fma_f32
      ah[j] += nm2 * hf;
    }
  };

  int it = g;
  for (; it + 6 < items; it += 8) {
    int r0 = node; float n0 = s2;
    if (it > 0) { r0 = erow[pe + it - 1]; n0 = enorm[pe + it - 1]; }
    int r1 = erow[pe + it + 1]; float n1 = enorm[pe + it + 1];
    int r2 = erow[pe + it + 3]; float n2 = enorm[pe + it + 3];
    int r3 = erow[pe + it + 5]; float n3 = enorm[pe + it + 5];
    uint4 x0 = X4[(size_t)r0 * 64 + soff]; uint4 h0 = H4[(size_t)r0 * 64 + soff];
    uint4 x1 = X4[(size_t)r1 * 64 + soff]; uint4 h1 = H4[(size_t)r1 * 64 + soff];
    uint4 x2 = X4[(size_t)r2 * 64 + soff]; uint4 h2 = H4[(size_t)r2 * 64 + soff];
    uint4 x3 = X4[(size_t)r3 * 64 + soff]; uint4 h3 = H4[(size_t)r3 * 64 + soff];
    accum(n0, x0, h0);
    accum(n1, x1, h1);
    accum(n2, x2, h2);
    accum(n3, x3, h3);
  }
  for (; it < items; it += 2) {
    int r = node; float nm = s2;
    if (it > 0) { r = erow[pe + it - 1]; nm = enorm[pe + it - 1]; }
    accum(nm, X4[(size_t)r * 64 + soff], H4[(size_t)r * 64 + soff]);
  }

  // single butterfly stage: combine the quarter's two groups
#pragma unroll
  for (int j = 0; j < 4; ++j) {
    ax[j].x += __shfl_xor(ax[j].x, 8, 64); ax[j].y += __shfl_xor(ax[j].y, 8, 64);
    ah[j].x += __shfl_xor(ah[j].x, 8, 64); ah[j].y += __shfl_xor(ah[j].y, 8, 64);
  }

  if (g == 0) {
    uint4 ox = {bf16pair(ax[0].x, ax[0].y), bf16pair(ax[1].x, ax[1].y),
                bf16pair(ax[2].x, ax[2].y), bf16pair(ax[3].x, ax[3].y)};
    ((uint4*)AXb)[(size_t)node * 64 + soff] = ox;
  } else {
    uint4 oh = {bf16pair(ah[0].x, ah[0].y), bf16pair(ah[1].x, ah[1].y),
                bf16pair(ah[2].x, ah[2].y), bf16pair(ah[3].x, ah[3].y)};
    ((uint4*)AHb)[(size_t)node * 64 + soff] = oh;
  }
}

__global__ __launch_bounds__(256) void k_agg_single_s3(const u16* __restrict__ Sb,
                                                       const int* __restrict__ ptr,
                                                       const int* __restrict__ erow,
                                                       const float* __restrict__ enorm,
                                                       const float* __restrict__ deg,
                                                       u16* __restrict__ Ab) {
  int bid = blockIdx.x;
  int slice = bid & 7, nb = bid >> 3;
  int w = threadIdx.x >> 6, lane = threadIdx.x & 63;
  int node = nb * 16 + w * 4 + (lane >> 4);
  int q = lane & 15;
  int g = q >> 3, cl = q & 7;
  int soff = slice * 8 + cl;
  const uint4* S4 = (const uint4*)Sb;
  float s = rsqrtf(deg[node]), s2 = s * s;
  int pe = ptr[node];
  int items = ptr[node + 1] - pe + 1;

  f32x2 ax[4] = {};
  auto accum = [&](float nm, uint4 xv) {
    unsigned xw[4] = {xv.x, xv.y, xv.z, xv.w};
    f32x2 nm2 = {nm, nm};
#pragma unroll
    for (int j = 0; j < 4; ++j) {
      f32x2 xf = {bflo(xw[j]), bfhi(xw[j])};
      ax[j] += nm2 * xf;
    }
  };

  int it = g;
  for (; it + 6 < items; it += 8) {
    int r0 = node; float n0 = s2;
    if (it > 0) { r0 = erow[pe + it - 1]; n0 = enorm[pe + it - 1]; }
    int r1 = erow[pe + it + 1]; float n1 = enorm[pe + it + 1];
    int r2 = erow[pe + it + 3]; float n2 = enorm[pe + it + 3];
    int r3 = erow[pe + it + 5]; float n3 = enorm[pe + it + 5];
    uint4 x0 = S4[(size_t)r0 * 64 + soff];
    uint4 x1 = S4[(size_t)r1 * 64 + soff];
    uint4 x2 = S4[(size_t)r2 * 64 + soff];
    uint4 x3 = S4[(size_t)r3 * 64 + soff];
    accum(n0, x0);
    accum(n1, x1);
    accum(n2, x2);
    accum(n3, x3);
  }
  for (; it < items; it += 2) {
    int r = node; float nm = s2;
    if (it > 0) { r = erow[pe + it - 1]; nm = enorm[pe + it - 1]; }
    accum(nm, S4[(size_t)r * 64 + soff]);
  }

#pragma unroll
  for (int j = 0; j < 4; ++j) {
    ax[j].x += __shfl_xor(ax[j].x, 8, 64); ax[j].y += __shfl_xor(ax[j].y, 8, 64);
  }

  if (g == 0) {
    uint4 ox = {bf16pair(ax[0].x, ax[0].y), bf16pair(ax[1].x, ax[1].y),
                bf16pair(ax[2].x, ax[2].y), bf16pair(ax[3].x, ax[3].y)};
    ((uint4*)Ab)[(size_t)node * 64 + soff] = ox;
  }
}

// ---------------- z&r GEMM: 8 col-blocks (z | r), round-9 proven structure ----------
// seg 0 (c 0-3):  Zb  = bf16(sigmoid(AX@Wxz + AH@Whz + bxz+bhz))
// seg 1 (c 4-7):  HRb = bf16(Hb * sigmoid(AX@Wxr + AH@Whr + bxr+bhr))
__global__ __launch_bounds__(256) void k_gemm_big(
    const u16* __restrict__ AXb, const u16* __restrict__ AHb,
    const u16* __restrict__ WtAll,
    const float* __restrict__ bxz, const float* __restrict__ bhz,
    const float* __restrict__ bxr, const float* __restrict__ bhr,
    const u16* __restrict__ Hb,
    u16* __restrict__ Zb, u16* __restrict__ HRb) {
  __shared__ unsigned char smem[32768];
  const int tid = threadIdx.x;
  const int lane = tid & 63, w = tid >> 6;
  const int wr = w >> 1, wc = w & 1;

  // bijective XCD-chunked map over 1256 = 157 row-blocks x 8 col-blocks (1256 = 8*157)
  const int q = 157;
  const int xcd = blockIdx.x & 7, ii = blockIdx.x >> 3;
  const int wk = xcd * q + ii;
  const int rowBase = (wk >> 3) * 128;
  const int c = wk & 7;
  const int seg = c >> 2;
  const int colBase = (c & 3) * 128;

  const u16* W1 = WtAll + (size_t)(seg ? 2 : 0) * 262144;
  const u16* W2 = WtAll + (size_t)(seg ? 3 : 1) * 262144;

  f32x4 acc[4][4] = {};

  const int lrow = lane & 15;
  const int lkb = (lane >> 4) << 4;
  const int swz = (lane & 7) << 4;
  const int srow = w * 32 + (lane >> 3);
  const int scol = (((lane & 7) ^ (lane >> 3)) << 4);

  for (int pass = 0; pass < 2; ++pass) {
    const u16* A = pass ? AHb : AXb;
    const u16* Wt = pass ? W2 : W1;
    const char* Abase = (const char*)A + (size_t)(rowBase + srow) * 1024 + scol;
    const char* Bbase = (const char*)Wt + (size_t)(colBase + srow) * 1024 + scol;
    for (int k0 = 0; k0 < 512; k0 += 64) {
      __syncthreads();
#pragma unroll
      for (int t = 0; t < 4; ++t) {
        gload16(Abase + (size_t)t * 8192 + k0 * 2, &smem[w * 4096 + t * 1024]);
        gload16(Bbase + (size_t)t * 8192 + k0 * 2, &smem[16384 + w * 4096 + t * 1024]);
      }
      __syncthreads();
#pragma unroll
      for (int ks = 0; ks < 2; ++ks) {
        bf16x8 af[4], bfr[4];
#pragma unroll
        for (int fm = 0; fm < 4; ++fm) {
          int row = wr * 64 + fm * 16 + lrow;
          af[fm] = *(const bf16x8*)&smem[row * 128 + (((ks << 6) + lkb) ^ swz)];
        }
#pragma unroll
        for (int fn = 0; fn < 4; ++fn) {
          int row = wc * 64 + fn * 16 + lrow;
          bfr[fn] = *(const bf16x8*)&smem[16384 + row * 128 + (((ks << 6) + lkb) ^ swz)];
        }
#pragma unroll
        for (int fm = 0; fm < 4; ++fm)
#pragma unroll
          for (int fn = 0; fn < 4; ++fn)
            acc[fm][fn] = __builtin_amdgcn_mfma_f32_16x16x32_bf16(af[fm], bfr[fn], acc[fm][fn], 0, 0, 0);
      }
    }
  }
  // epilogue: col=lane&15, row=(lane>>4)*4+reg
#pragma unroll
  for (int fm = 0; fm < 4; ++fm) {
    int rbase = rowBase + wr * 64 + fm * 16 + ((lane >> 4) << 2);
#pragma unroll
    for (int fn = 0; fn < 4; ++fn) {
      int col = colBase + wc * 64 + fn * 16 + lrow;
      float bb = seg ? (bxr[col] + bhr[col]) : (bxz[col] + bhz[col]);
#pragma unroll
      for (int r = 0; r < 4; ++r) {
        int row = rbase + r;
        if (row >= NN) continue;
        size_t idx = (size_t)row * 512 + col;
        float a = acc[fm][fn][r] + bb;
        if (seg == 0) {
          Zb[idx] = bf16one(sigmoidf_(a));
        } else {
          HRb[idx] = bf16one(bf2f(Hb[idx]) * sigmoidf_(a));
        }
      }
    }
  }
}

// ---------------- final GEMM: 2-pass K, out = z*h + (1-z)*tanh(AHR@Whh + AX@Wxh + b) --
__global__ __launch_bounds__(256) void k_gemm_fin(
    const u16* __restrict__ AHRb, const u16* __restrict__ AXb,
    const u16* __restrict__ WtAll,
    const float* __restrict__ bxh, const float* __restrict__ bhh,
    const u16* __restrict__ Hb, const u16* __restrict__ Zb,
    float* __restrict__ out) {
  __shared__ unsigned char smem[32768];
  const int tid = threadIdx.x;
  const int lane = tid & 63, w = tid >> 6;
  const int wr = w >> 1, wc = w & 1;

  const int q = 78, r8 = 4;  // 628 = 8*78+4
  const int xcd = blockIdx.x & 7, ii = blockIdx.x >> 3;
  const int start = (xcd < r8) ? xcd * (q + 1) : r8 * (q + 1) + (xcd - r8) * q;
  const int wk = start + ii;
  const int rowBase = (wk >> 2) * 128;
  const int colBase = (wk & 3) * 128;

  f32x4 acc[4][4] = {};

  const int lrow = lane & 15;
  const int lkb = (lane >> 4) << 4;
  const int swz = (lane & 7) << 4;
  const int srow = w * 32 + (lane >> 3);
  const int scol = (((lane & 7) ^ (lane >> 3)) << 4);

  for (int pass = 0; pass < 2; ++pass) {
    const u16* A  = pass ? AXb : AHRb;
    const u16* Wt = WtAll + (size_t)(pass ? 4 : 5) * 262144;  // Whh then Wxh
    const char* Abase = (const char*)A + (size_t)(rowBase + srow) * 1024 + scol;
    const char* Bbase = (const char*)Wt + (size_t)(colBase + srow) * 1024 + scol;
    for (int k0 = 0; k0 < 512; k0 += 64) {
      __syncthreads();
#pragma unroll
      for (int t = 0; t < 4; ++t) {
        gload16(Abase + (size_t)t * 8192 + k0 * 2, &smem[w * 4096 + t * 1024]);
        gload16(Bbase + (size_t)t * 8192 + k0 * 2, &smem[16384 + w * 4096 + t * 1024]);
      }
      __syncthreads();
#pragma unroll
      for (int ks = 0; ks < 2; ++ks) {
        bf16x8 af[4], bfr[4];
#pragma unroll
        for (int fm = 0; fm < 4; ++fm) {
          int row = wr * 64 + fm * 16 + lrow;
          af[fm] = *(const bf16x8*)&smem[row * 128 + (((ks << 6) + lkb) ^ swz)];
        }
#pragma unroll
        for (int fn = 0; fn < 4; ++fn) {
          int row = wc * 64 + fn * 16 + lrow;
          bfr[fn] = *(const bf16x8*)&smem[16384 + row * 128 + (((ks << 6) + lkb) ^ swz)];
        }
#pragma unroll
        for (int fm = 0; fm < 4; ++fm)
#pragma unroll
          for (int fn = 0; fn < 4; ++fn)
            acc[fm][fn] = __builtin_amdgcn_mfma_f32_16x16x32_bf16(af[fm], bfr[fn], acc[fm][fn], 0, 0, 0);
      }
    }
  }
#pragma unroll
  for (int fm = 0; fm < 4; ++fm) {
    int rbase = rowBase + wr * 64 + fm * 16 + ((lane >> 4) << 2);
#pragma unroll
    for (int fn = 0; fn < 4; ++fn) {
      int col = colBase + wc * 64 + fn * 16 + lrow;
      float bb = bxh[col] + bhh[col];
#pragma unroll
      for (int r = 0; r < 4; ++r) {
        int row = rbase + r;
        if (row >= NN) continue;
        size_t idx = (size_t)row * 512 + col;
        float t = tanhf_(acc[fm][fn][r] + bb);
        float z = bf2f(Zb[idx]);
        float h = bf2f(Hb[idx]);
        out[idx] = z * h + (1.f - z) * t;
      }
    }
  }
}

extern "C" void kernel_launch(void* const* d_in, const int* in_sizes, int n_in,
                              void* d_out, int out_size, void* d_ws, size_t ws_size,
                              hipStream_t stream) {
  const float* X   = (const float*)d_in[0];
  const int*   ei  = (const int*)d_in[1];
  const float* ew  = (const float*)d_in[2];
  const float* H   = (const float*)d_in[3];
  const float* Wxz = (const float*)d_in[4];  const float* bxz = (const float*)d_in[5];
  const float* Whz = (const float*)d_in[6];  const float* bhz = (const float*)d_in[7];
  const float* Wxr = (const float*)d_in[8];  const float* bxr = (const float*)d_in[9];
  const float* Whr = (const float*)d_in[10]; const float* bhr = (const float*)d_in[11];
  const float* Wxh = (const float*)d_in[12]; const float* bxh = (const float*)d_in[13];
  const float* Whh = (const float*)d_in[14]; const float* bhh = (const float*)d_in[15];
  const int* row = ei;
  const int* col = ei + NE;
  float* out = (float*)d_out;

  char* base = (char*)d_ws;
  size_t o = 0;
  auto alloc = [&](size_t b) { char* p = base + o; o += (b + 255) & ~(size_t)255; return p; };
  u16* Xb   = (u16*)alloc((size_t)NP * DD * 2);  // aliases AHRb (Xb dead after agg_dual)
  u16* Hb   = (u16*)alloc((size_t)NP * DD * 2);  // live through gemm_fin epilogue
  u16* AXb  = (u16*)alloc((size_t)NP * DD * 2);  // live through gemm_fin pass 2
  u16* AHb  = (u16*)alloc((size_t)NP * DD * 2);
  u16* HRb  = (u16*)alloc((size_t)NP * DD * 2);
  u16* Zb   = (u16*)alloc((size_t)NP * DD * 2);
  u16* WtAll= (u16*)alloc((size_t)6 * 512 * 512 * 2);
  float* deg  = (float*)alloc(NN * 4);
  int*   cnt  = (int*)alloc(NN * 4);
  int*   ptr  = (int*)alloc((NN + 1) * 4);
  int*   pos  = (int*)alloc(NN * 4);
  int*   erow = (int*)alloc(NE * 4);
  float* enorm= (float*)alloc(NE * 4);
  u16* AHRb = Xb;   // Xb dead after k_agg_dual_s3

  dim3 b256(256);
  int gE = (NE + 255) / 256;

  // fused setup: cvt X/H -> bf16 | init deg/cnt | 6 weight transposes
  k_setup<<<CVT_B + INIT_B + WT_B, b256, 0, stream>>>(
      X, H, Xb, Hb, Wxz, Whz, Wxr, Whr, Wxh, Whh, WtAll, deg, cnt);

  // CSR build
  k_accum<<<gE, b256, 0, stream>>>(col, ew, deg, cnt);
  k_scan<<<1, 1024, 0, stream>>>(cnt, ptr, pos);
  k_scatter<<<gE, b256, 0, stream>>>(row, col, ew, deg, pos, erow, enorm);

  // AX = Agg(X), AH = Agg(H): 4 nodes/wave, 2 item-groups, unroll-4
  k_agg_dual_s3<<<10000, b256, 0, stream>>>(Xb, Hb, ptr, erow, enorm, deg, AXb, AHb);

  // z & r GEMM -> Zb, HRb
  k_gemm_big<<<1256, b256, 0, stream>>>(AXb, AHb, WtAll, bxz, bhz, bxr, bhr,
                                        Hb, Zb, HRb);

  // AHR = Agg(HR)
  k_agg_single_s3<<<10000, b256, 0, stream>>>(HRb, ptr, erow, enorm, deg, AHRb);

  // out = z*h + (1-z)*tanh(AHR@Whh + AX@Wxh + bxh + bhh)
  k_gemm_fin<<<628, b256, 0, stream>>>(AHRb, AXb, WtAll, bxh, bhh,
                                       Hb, Zb, out);
}

// Round 15
// 320.103 us; speedup vs baseline: 1.4278x; 1.0221x over previous
//
#include <hip/hip_runtime.h>

#define NN 20000
#define NP 20096   // padded rows (multiple of 128)
#define NE 320000
#define DD 512

typedef __bf16 bf16x8 __attribute__((ext_vector_type(8)));
typedef float f32x4 __attribute__((ext_vector_type(4)));
typedef float f32x2 __attribute__((ext_vector_type(2)));
typedef unsigned short u16;

// fast transcendentals: v_exp_f32 + v_rcp_f32, branchless
__device__ __forceinline__ float sigmoidf_(float x) {
  return __builtin_amdgcn_rcpf(1.f + __expf(-x));
}
__device__ __forceinline__ float tanhf_(float x) {
  float xc = fminf(fmaxf(x, -15.f), 15.f);
  float u = __expf(2.f * xc);
  return (u - 1.f) * __builtin_amdgcn_rcpf(u + 1.f);
}

__device__ __forceinline__ unsigned bf16pair(float a, float b) {
  unsigned ua = __builtin_bit_cast(unsigned, a);
  unsigned ub = __builtin_bit_cast(unsigned, b);
  ua = (ua + 0x7FFFu + ((ua >> 16) & 1u)) >> 16;
  ub = (ub + 0x7FFFu + ((ub >> 16) & 1u)) >> 16;
  return ua | (ub << 16);
}
__device__ __forceinline__ u16 bf16one(float a) {
  unsigned ua = __builtin_bit_cast(unsigned, a);
  return (u16)((ua + 0x7FFFu + ((ua >> 16) & 1u)) >> 16);
}
__device__ __forceinline__ float bflo(unsigned w) { return __builtin_bit_cast(float, w << 16); }
__device__ __forceinline__ float bfhi(unsigned w) { return __builtin_bit_cast(float, w & 0xFFFF0000u); }
__device__ __forceinline__ float bf2f(u16 v) { return __builtin_bit_cast(float, (unsigned)v << 16); }

__device__ __forceinline__ void gload16(const void* g, void* l) {
  __builtin_amdgcn_global_load_lds(
      (const __attribute__((address_space(1))) unsigned int*)g,
      (__attribute__((address_space(3))) unsigned int*)l, 16, 0, 0);
}

// ---------------- fused setup: cvt(X,H)->bf16 | init deg/cnt | 6 weight transposes ----
#define CVT_B 10000   // 2*NN*DD/8/256
#define INIT_B 79     // ceil(NN/256)
#define WT_B 1536     // 6 * 16 * 16
__global__ __launch_bounds__(256) void k_setup(
    const float* __restrict__ X, const float* __restrict__ H,
    u16* __restrict__ Xb, u16* __restrict__ Hb,
    const float* __restrict__ W0, const float* __restrict__ W1,
    const float* __restrict__ W2, const float* __restrict__ W3,
    const float* __restrict__ W4, const float* __restrict__ W5,
    u16* __restrict__ T, float* __restrict__ deg, int* __restrict__ cnt) {
  __shared__ float t[32][33];
  int b = blockIdx.x;
  if (b < CVT_B) {
    const int n8 = NN * DD / 8;
    int i = b * 256 + threadIdx.x;
    const float* src = (i < n8) ? X : H;
    u16* dst = (i < n8) ? Xb : Hb;
    int k = (i < n8) ? i : i - n8;
    const float4* s = (const float4*)src;
    float4 v0 = s[k * 2], v1 = s[k * 2 + 1];
    uint4 o = {bf16pair(v0.x, v0.y), bf16pair(v0.z, v0.w),
               bf16pair(v1.x, v1.y), bf16pair(v1.z, v1.w)};
    ((uint4*)dst)[k] = o;
  } else if (b < CVT_B + INIT_B) {
    int i = (b - CVT_B) * 256 + threadIdx.x;
    if (i < NN) { deg[i] = 1.0f; cnt[i] = 0; }
  } else {
    int wb = b - CVT_B - INIT_B;          // [0, 1536)
    const float* Wsrc;
    switch (wb >> 8) {
      case 0: Wsrc = W0; break; case 1: Wsrc = W1; break; case 2: Wsrc = W2; break;
      case 3: Wsrc = W3; break; case 4: Wsrc = W4; break; default: Wsrc = W5; break;
    }
    u16* Wt = T + (size_t)(wb >> 8) * 262144;
    int rb = wb & 255;
    int kb = (rb & 15) * 32, nb = (rb >> 4) * 32;
    int tx = threadIdx.x & 31, ty = threadIdx.x >> 5;
#pragma unroll
    for (int i2 = 0; i2 < 4; ++i2)
      t[ty * 4 + i2][tx] = Wsrc[(size_t)(kb + ty * 4 + i2) * 512 + nb + tx];
    __syncthreads();
#pragma unroll
    for (int i2 = 0; i2 < 4; ++i2)
      Wt[(size_t)(nb + ty * 4 + i2) * 512 + kb + tx] = bf16one(t[tx][ty * 4 + i2]);
  }
}

// ---------------- degree / CSR ----------------
__global__ void k_accum(const int* col, const float* w, float* deg, int* cnt) {
  int e = blockIdx.x * 256 + threadIdx.x;
  if (e < NE) {
    int c = col[e];
    atomicAdd(&deg[c], w[e]);
    atomicAdd(&cnt[c], 1);
  }
}

__global__ void k_scan(const int* cnt, int* ptr, int* pos) {
  __shared__ int sdata[1024];
  const int ITEMS = (NN + 1023) / 1024;
  int tid = threadIdx.x;
  int base = tid * ITEMS;
  int s = 0;
  for (int j = 0; j < ITEMS; ++j) { int i = base + j; if (i < NN) s += cnt[i]; }
  sdata[tid] = s;
  __syncthreads();
  for (int off = 1; off < 1024; off <<= 1) {
    int v = 0;
    if (tid >= off) v = sdata[tid - off];
    __syncthreads();
    sdata[tid] += v;
    __syncthreads();
  }
  int run = (tid == 0) ? 0 : sdata[tid - 1];
  for (int j = 0; j < ITEMS; ++j) {
    int i = base + j;
    if (i < NN) { ptr[i] = run; pos[i] = run; run += cnt[i]; }
  }
  if (tid == 0) ptr[NN] = NE;
}

__global__ void k_scatter(const int* row, const int* col, const float* w, const float* deg,
                          int* pos, int* erow, float* enorm) {
  int e = blockIdx.x * 256 + threadIdx.x;
  if (e < NE) {
    int r = row[e], c = col[e];
    int slot = atomicAdd(&pos[c], 1);
    erow[slot] = r;
    enorm[slot] = rsqrtf(deg[r]) * w[e] * rsqrtf(deg[c]);
  }
}

// ---------------- XCD-sliced single-array aggregation ----------------
// grid 2*AGG_B: blocks [0,AGG_B) aggregate SA->DA, [AGG_B,2*AGG_B) SB->DB
// (time-separated so each XCD's L2 holds ONE 2.56MB array slice).
// quarter (16 lanes) = one node; group g in {0,1}: g0 = self + odd-offset edges,
// g1 = even-offset edges. unroll-4. Tail: ONE shfl_xor stage (stride 8).
#define AGG_B 10000
__global__ __launch_bounds__(256) void k_agg_one(const u16* __restrict__ SA,
                                                 const u16* __restrict__ SB,
                                                 u16* __restrict__ DA,
                                                 u16* __restrict__ DB,
                                                 const int* __restrict__ ptr,
                                                 const int* __restrict__ erow,
                                                 const float* __restrict__ enorm,
                                                 const float* __restrict__ deg) {
  int bid = blockIdx.x;
  bool second = bid >= AGG_B;
  const uint4* S4 = (const uint4*)(second ? SB : SA);
  uint4* D4 = (uint4*)(second ? DB : DA);
  int b = second ? bid - AGG_B : bid;
  int slice = b & 7, nb = b >> 3;
  int w = threadIdx.x >> 6, lane = threadIdx.x & 63;
  int node = nb * 16 + w * 4 + (lane >> 4);
  int q = lane & 15;
  int g = q >> 3, cl = q & 7;
  int soff = slice * 8 + cl;

  float s = rsqrtf(deg[node]), s2 = s * s;
  int pe = ptr[node], e1 = ptr[node + 1];

  f32x2 ax[4] = {};
  auto accum = [&](float nm, uint4 xv) {
    unsigned xw[4] = {xv.x, xv.y, xv.z, xv.w};
    f32x2 nm2 = {nm, nm};
#pragma unroll
    for (int j = 0; j < 4; ++j) {
      f32x2 xf = {bflo(xw[j]), bfhi(xw[j])};
      ax[j] += nm2 * xf;   // v_pk_fma_f32
    }
  };

  if (g == 0) accum(s2, S4[(size_t)node * 64 + soff]);   // self-loop
  int e = pe + 1 - g;                                    // g0: odd offsets, g1: even
  for (; e + 6 < e1; e += 8) {
    int r0 = erow[e];     float n0 = enorm[e];
    int r1 = erow[e + 2]; float n1 = enorm[e + 2];
    int r2 = erow[e + 4]; float n2 = enorm[e + 4];
    int r3 = erow[e + 6]; float n3 = enorm[e + 6];
    uint4 x0 = S4[(size_t)r0 * 64 + soff];
    uint4 x1 = S4[(size_t)r1 * 64 + soff];
    uint4 x2 = S4[(size_t)r2 * 64 + soff];
    uint4 x3 = S4[(size_t)r3 * 64 + soff];
    accum(n0, x0);
    accum(n1, x1);
    accum(n2, x2);
    accum(n3, x3);
  }
  for (; e < e1; e += 2) accum(enorm[e], S4[(size_t)erow[e] * 64 + soff]);

  // single butterfly stage: combine the quarter's two groups
#pragma unroll
  for (int j = 0; j < 4; ++j) {
    ax[j].x += __shfl_xor(ax[j].x, 8, 64);
    ax[j].y += __shfl_xor(ax[j].y, 8, 64);
  }

  if (g == 0) {
    uint4 ox = {bf16pair(ax[0].x, ax[0].y), bf16pair(ax[1].x, ax[1].y),
                bf16pair(ax[2].x, ax[2].y), bf16pair(ax[3].x, ax[3].y)};
    D4[(size_t)node * 64 + soff] = ox;
  }
}

// ---------------- z&r GEMM: 8 col-blocks (z | r), round-9 proven structure ----------
// seg 0 (c 0-3):  Zb  = bf16(sigmoid(AX@Wxz + AH@Whz + bxz+bhz))
// seg 1 (c 4-7):  HRb = bf16(Hb * sigmoid(AX@Wxr + AH@Whr + bxr+bhr))
__global__ __launch_bounds__(256) void k_gemm_big(
    const u16* __restrict__ AXb, const u16* __restrict__ AHb,
    const u16* __restrict__ WtAll,
    const float* __restrict__ bxz, const float* __restrict__ bhz,
    const float* __restrict__ bxr, const float* __restrict__ bhr,
    const u16* __restrict__ Hb,
    u16* __restrict__ Zb, u16* __restrict__ HRb) {
  __shared__ unsigned char smem[32768];
  const int tid = threadIdx.x;
  const int lane = tid & 63, w = tid >> 6;
  const int wr = w >> 1, wc = w & 1;

  // bijective XCD-chunked map over 1256 = 157 row-blocks x 8 col-blocks (1256 = 8*157)
  const int q = 157;
  const int xcd = blockIdx.x & 7, ii = blockIdx.x >> 3;
  const int wk = xcd * q + ii;
  const int rowBase = (wk >> 3) * 128;
  const int c = wk & 7;
  const int seg = c >> 2;
  const int colBase = (c & 3) * 128;

  const u16* W1 = WtAll + (size_t)(seg ? 2 : 0) * 262144;
  const u16* W2 = WtAll + (size_t)(seg ? 3 : 1) * 262144;

  f32x4 acc[4][4] = {};

  const int lrow = lane & 15;
  const int lkb = (lane >> 4) << 4;
  const int swz = (lane & 7) << 4;
  const int srow = w * 32 + (lane >> 3);
  const int scol = (((lane & 7) ^ (lane >> 3)) << 4);

  for (int pass = 0; pass < 2; ++pass) {
    const u16* A = pass ? AHb : AXb;
    const u16* Wt = pass ? W2 : W1;
    const char* Abase = (const char*)A + (size_t)(rowBase + srow) * 1024 + scol;
    const char* Bbase = (const char*)Wt + (size_t)(colBase + srow) * 1024 + scol;
    for (int k0 = 0; k0 < 512; k0 += 64) {
      __syncthreads();
#pragma unroll
      for (int t = 0; t < 4; ++t) {
        gload16(Abase + (size_t)t * 8192 + k0 * 2, &smem[w * 4096 + t * 1024]);
        gload16(Bbase + (size_t)t * 8192 + k0 * 2, &smem[16384 + w * 4096 + t * 1024]);
      }
      __syncthreads();
#pragma unroll
      for (int ks = 0; ks < 2; ++ks) {
        bf16x8 af[4], bfr[4];
#pragma unroll
        for (int fm = 0; fm < 4; ++fm) {
          int row = wr * 64 + fm * 16 + lrow;
          af[fm] = *(const bf16x8*)&smem[row * 128 + (((ks << 6) + lkb) ^ swz)];
        }
#pragma unroll
        for (int fn = 0; fn < 4; ++fn) {
          int row = wc * 64 + fn * 16 + lrow;
          bfr[fn] = *(const bf16x8*)&smem[16384 + row * 128 + (((ks << 6) + lkb) ^ swz)];
        }
#pragma unroll
        for (int fm = 0; fm < 4; ++fm)
#pragma unroll
          for (int fn = 0; fn < 4; ++fn)
            acc[fm][fn] = __builtin_amdgcn_mfma_f32_16x16x32_bf16(af[fm], bfr[fn], acc[fm][fn], 0, 0, 0);
      }
    }
  }
  // epilogue: col=lane&15, row=(lane>>4)*4+reg
#pragma unroll
  for (int fm = 0; fm < 4; ++fm) {
    int rbase = rowBase + wr * 64 + fm * 16 + ((lane >> 4) << 2);
#pragma unroll
    for (int fn = 0; fn < 4; ++fn) {
      int col = colBase + wc * 64 + fn * 16 + lrow;
      float bb = seg ? (bxr[col] + bhr[col]) : (bxz[col] + bhz[col]);
#pragma unroll
      for (int r = 0; r < 4; ++r) {
        int row = rbase + r;
        if (row >= NN) continue;
        size_t idx = (size_t)row * 512 + col;
        float a = acc[fm][fn][r] + bb;
        if (seg == 0) {
          Zb[idx] = bf16one(sigmoidf_(a));
        } else {
          HRb[idx] = bf16one(bf2f(Hb[idx]) * sigmoidf_(a));
        }
      }
    }
  }
}

// ---------------- final GEMM: 2-pass K, out = z*h + (1-z)*tanh(AHR@Whh + AX@Wxh + b) --
__global__ __launch_bounds__(256) void k_gemm_fin(
    const u16* __restrict__ AHRb, const u16* __restrict__ AXb,
    const u16* __restrict__ WtAll,
    const float* __restrict__ bxh, const float* __restrict__ bhh,
    const u16* __restrict__ Hb, const u16* __restrict__ Zb,
    float* __restrict__ out) {
  __shared__ unsigned char smem[32768];
  const int tid = threadIdx.x;
  const int lane = tid & 63, w = tid >> 6;
  const int wr = w >> 1, wc = w & 1;

  const int q = 78, r8 = 4;  // 628 = 8*78+4
  const int xcd = blockIdx.x & 7, ii = blockIdx.x >> 3;
  const int start = (xcd < r8) ? xcd * (q + 1) : r8 * (q + 1) + (xcd - r8) * q;
  const int wk = start + ii;
  const int rowBase = (wk >> 2) * 128;
  const int colBase = (wk & 3) * 128;

  f32x4 acc[4][4] = {};

  const int lrow = lane & 15;
  const int lkb = (lane >> 4) << 4;
  const int swz = (lane & 7) << 4;
  const int srow = w * 32 + (lane >> 3);
  const int scol = (((lane & 7) ^ (lane >> 3)) << 4);

  for (int pass = 0; pass < 2; ++pass) {
    const u16* A  = pass ? AXb : AHRb;
    const u16* Wt = WtAll + (size_t)(pass ? 4 : 5) * 262144;  // Whh then Wxh
    const char* Abase = (const char*)A + (size_t)(rowBase + srow) * 1024 + scol;
    const char* Bbase = (const char*)Wt + (size_t)(colBase + srow) * 1024 + scol;
    for (int k0 = 0; k0 < 512; k0 += 64) {
      __syncthreads();
#pragma unroll
      for (int t = 0; t < 4; ++t) {
        gload16(Abase + (size_t)t * 8192 + k0 * 2, &smem[w * 4096 + t * 1024]);
        gload16(Bbase + (size_t)t * 8192 + k0 * 2, &smem[16384 + w * 4096 + t * 1024]);
      }
      __syncthreads();
#pragma unroll
      for (int ks = 0; ks < 2; ++ks) {
        bf16x8 af[4], bfr[4];
#pragma unroll
        for (int fm = 0; fm < 4; ++fm) {
          int row = wr * 64 + fm * 16 + lrow;
          af[fm] = *(const bf16x8*)&smem[row * 128 + (((ks << 6) + lkb) ^ swz)];
        }
#pragma unroll
        for (int fn = 0; fn < 4; ++fn) {
          int row = wc * 64 + fn * 16 + lrow;
          bfr[fn] = *(const bf16x8*)&smem[16384 + row * 128 + (((ks << 6) + lkb) ^ swz)];
        }
#pragma unroll
        for (int fm = 0; fm < 4; ++fm)
#pragma unroll
          for (int fn = 0; fn < 4; ++fn)
            acc[fm][fn] = __builtin_amdgcn_mfma_f32_16x16x32_bf16(af[fm], bfr[fn], acc[fm][fn], 0, 0, 0);
      }
    }
  }
#pragma unroll
  for (int fm = 0; fm < 4; ++fm) {
    int rbase = rowBase + wr * 64 + fm * 16 + ((lane >> 4) << 2);
#pragma unroll
    for (int fn = 0; fn < 4; ++fn) {
      int col = colBase + wc * 64 + fn * 16 + lrow;
      float bb = bxh[col] + bhh[col];
#pragma unroll
      for (int r = 0; r < 4; ++r) {
        int row = rbase + r;
        if (row >= NN) continue;
        size_t idx = (size_t)row * 512 + col;
        float t = tanhf_(acc[fm][fn][r] + bb);
        float z = bf2f(Zb[idx]);
        float h = bf2f(Hb[idx]);
        out[idx] = z * h + (1.f - z) * t;
      }
    }
  }
}

extern "C" void kernel_launch(void* const* d_in, const int* in_sizes, int n_in,
                              void* d_out, int out_size, void* d_ws, size_t ws_size,
                              hipStream_t stream) {
  const float* X   = (const float*)d_in[0];
  const int*   ei  = (const int*)d_in[1];
  const float* ew  = (const float*)d_in[2];
  const float* H   = (const float*)d_in[3];
  const float* Wxz = (const float*)d_in[4];  const float* bxz = (const float*)d_in[5];
  const float* Whz = (const float*)d_in[6];  const float* bhz = (const float*)d_in[7];
  const float* Wxr = (const float*)d_in[8];  const float* bxr = (const float*)d_in[9];
  const float* Whr = (const float*)d_in[10]; const float* bhr = (const float*)d_in[11];
  const float* Wxh = (const float*)d_in[12]; const float* bxh = (const float*)d_in[13];
  const float* Whh = (const float*)d_in[14]; const float* bhh = (const float*)d_in[15];
  const int* row = ei;
  const int* col = ei + NE;
  float* out = (float*)d_out;

  char* base = (char*)d_ws;
  size_t o = 0;
  auto alloc = [&](size_t b) { char* p = base + o; o += (b + 255) & ~(size_t)255; return p; };
  u16* Xb   = (u16*)alloc((size_t)NP * DD * 2);  // aliases AHRb (Xb dead after agg X/H)
  u16* Hb   = (u16*)alloc((size_t)NP * DD * 2);  // live through gemm_fin epilogue
  u16* AXb  = (u16*)alloc((size_t)NP * DD * 2);  // live through gemm_fin pass 2
  u16* AHb  = (u16*)alloc((size_t)NP * DD * 2);
  u16* HRb  = (u16*)alloc((size_t)NP * DD * 2);
  u16* Zb   = (u16*)alloc((size_t)NP * DD * 2);
  u16* WtAll= (u16*)alloc((size_t)6 * 512 * 512 * 2);
  float* deg  = (float*)alloc(NN * 4);
  int*   cnt  = (int*)alloc(NN * 4);
  int*   ptr  = (int*)alloc((NN + 1) * 4);
  int*   pos  = (int*)alloc(NN * 4);
  int*   erow = (int*)alloc(NE * 4);
  float* enorm= (float*)alloc(NE * 4);
  u16* AHRb = Xb;   // Xb dead after the X/H aggregation

  dim3 b256(256);
  int gE = (NE + 255) / 256;

  // fused setup: cvt X/H -> bf16 | init deg/cnt | 6 weight transposes
  k_setup<<<CVT_B + INIT_B + WT_B, b256, 0, stream>>>(
      X, H, Xb, Hb, Wxz, Whz, Wxr, Whr, Wxh, Whh, WtAll, deg, cnt);

  // CSR build
  k_accum<<<gE, b256, 0, stream>>>(col, ew, deg, cnt);
  k_scan<<<1, 1024, 0, stream>>>(cnt, ptr, pos);
  k_scatter<<<gE, b256, 0, stream>>>(row, col, ew, deg, pos, erow, enorm);

  // AX = Agg(X) then AH = Agg(H), time-separated in one launch (L2-slice-fit)
  k_agg_one<<<2 * AGG_B, b256, 0, stream>>>(Xb, Hb, AXb, AHb, ptr, erow, enorm, deg);

  // z & r GEMM -> Zb, HRb
  k_gemm_big<<<1256, b256, 0, stream>>>(AXb, AHb, WtAll, bxz, bhz, bxr, bhr,
                                        Hb, Zb, HRb);

  // AHR = Agg(HR)
  k_agg_one<<<AGG_B, b256, 0, stream>>>(HRb, HRb, AHRb, AHRb, ptr, erow, enorm, deg);

  // out = z*h + (1-z)*tanh(AHR@Whh + AX@Wxh + bxh + bhh)
  k_gemm_fin<<<628, b256, 0, stream>>>(AHRb, AXb, WtAll, bxh, bhh,
                                       Hb, Zb, out);
}